// Round 5
// baseline (1387.508 us; speedup 1.0000x reference)
//
#include <hip/hip_runtime.h>

#define TT 512
#define HH 256
#define EE 128
#define BB 256
#define CC 64
#define VV 50000

// workspace offsets (bytes), all 256-aligned
#define OFF_EMB   0ull           // 50000*128       = 6,400,000   (emb as fp8)
#define OFF_WMX   6400000ull     // 16*4*2*64*32    =   262,144   (W_hh fp8 MX frags)
#define OFF_WX    6662144ull     // 16*4*4*64*8     =   131,072   (W_ih fp8 16x16x32 frags)
#define OFF_BIAS  6793216ull     // 1024*4          =     4,096   (b_ih+b_hh, permuted)
#define OFF_WLIN  6797312ull     // 4*8*64*8*2      =    16,384   (W_lin bf16 frags)
#define OFF_LSTM  6813696ull     // 256*512*256*2   = 67,108,864  (lstm_out bf16)
#define OFF_LOG   73922560ull    // 256*512*64*4    = 33,554,432  (logits f32)
#define WS_NEED   107476992ull

typedef __attribute__((ext_vector_type(4))) float    f32x4;
typedef __attribute__((ext_vector_type(2))) float    f32x2;
typedef __attribute__((ext_vector_type(4))) unsigned u32x4;
typedef __attribute__((ext_vector_type(2))) unsigned u32x2;
typedef __attribute__((ext_vector_type(8))) int      i32x8;
typedef __bf16 bf16x8_t __attribute__((ext_vector_type(8)));

__device__ __forceinline__ float rcp_f(float x) { return __builtin_amdgcn_rcpf(x); }
__device__ __forceinline__ unsigned short to_bf16(float f) {
  unsigned u = __float_as_uint(f);
  return (unsigned short)((u + 0x7fffu + ((u >> 16) & 1u)) >> 16);
}
__device__ __forceinline__ float sigm(float x) { return rcp_f(1.f + __expf(-x)); }
__device__ __forceinline__ float tanhf_(float x) { return 2.f * rcp_f(1.f + __expf(-2.f * x)) - 1.f; }
__device__ __forceinline__ f32x4 mfma8(long a, long b, f32x4 c) {
  return __builtin_amdgcn_mfma_f32_16x16x32_fp8_fp8(a, b, c, 0, 0, 0);
}
// MX-scaled fp8 GEMM, K=128, all scale exponents = 127 (x1.0) -> plain fp8 at 2x rate
__device__ __forceinline__ f32x4 mfma_mx(i32x8 a, i32x8 b, f32x4 c) {
  return __builtin_amdgcn_mfma_scale_f32_16x16x128_f8f6f4(
      a, b, c, 0, 0, 0, 0x7f7f7f7f, 0, 0x7f7f7f7f);
}

// ---------------- prep: emb fp32 -> fp8 e4m3 (unscaled) ----------------
__global__ void prep_emb(const float* __restrict__ emb, unsigned* __restrict__ out) {
  const int stride = gridDim.x * blockDim.x;
  for (int u = blockIdx.x * blockDim.x + threadIdx.x; u < (VV * EE / 4); u += stride) {
    const f32x4 f = ((const f32x4*)emb)[u];
    int r = __builtin_amdgcn_cvt_pk_fp8_f32(f[0], f[1], 0, false);
    r = __builtin_amdgcn_cvt_pk_fp8_f32(f[2], f[3], r, true);
    out[u] = (unsigned)r;
  }
}

// ------- prep: W_hh*64 -> fp8 MX B-fragments (16x16x128) -------
__global__ void prep_wmx(const float* __restrict__ Whh, unsigned char* __restrict__ wf) {
  const int id = blockIdx.x * 256 + threadIdx.x;  // exactly 262144 threads
  const int b = id & 31, l = (id >> 5) & 63;
  const int T = (id >> 11) & 1, q = (id >> 12) & 3, w = id >> 14;
  const int grow = q * 256 + w * 16 + (l & 15);
  const int k = T * 128 + ((l >> 4) << 5) + b;
  const int r = __builtin_amdgcn_cvt_pk_fp8_f32(64.f * Whh[grow * HH + k], 0.f, 0, false);
  wf[id] = (unsigned char)(r & 0xff);
}

// ------- prep: W_ih*1024 -> fp8 16x16x32 B-fragments (4 K-tiles of 32) -------
__global__ void prep_wx(const float* __restrict__ Wih, unsigned char* __restrict__ wf) {
  const int id = blockIdx.x * 256 + threadIdx.x;  // exactly 131072 threads
  const int j = id & 7, l = (id >> 3) & 63;
  const int kk = (id >> 9) & 3, q = (id >> 11) & 3, w = id >> 13;
  const int grow = q * 256 + w * 16 + (l & 15);
  const int e = kk * 32 + ((l >> 4) << 3) + j;
  const int r = __builtin_amdgcn_cvt_pk_fp8_f32(1024.f * Wih[grow * EE + e], 0.f, 0, false);
  wf[id] = (unsigned char)(r & 0xff);
}

__global__ void prep_bias(const float* __restrict__ bih, const float* __restrict__ bhh,
                          float* __restrict__ bp) {
  const int n = blockIdx.x * 256 + threadIdx.x;  // 1024 threads
  const int w = n >> 6, q = (n >> 4) & 3, c = n & 15;
  const int g = q * 256 + w * 16 + c;
  bp[n] = bih[g] + bhh[g];
}

__global__ void prep_wlin(const float* __restrict__ Wlin, unsigned short* __restrict__ wl) {
  const int id = blockIdx.x * 256 + threadIdx.x;  // 16384 threads
  const int j = id & 7, l = (id >> 3) & 63;
  const int kk = (id >> 9) & 7, q = id >> 12;
  const int c = q * 16 + (l & 15);
  const int k = kk * 32 + ((l >> 4) << 3) + j;
  wl[id] = to_bf16(Wlin[c * HH + k]);
}

// ---------------- persistent LSTM scan: 64 blocks x 1024 thr, 4 seqs/block ----------------
// A buffer (double, 6144 B each): bytes 0..4095 = h region (MX frag order, rows=seqs,
// rows 4..15 permanently zero); bytes 4096..6143 = x region (16x16x32 frag order).
//   h byte(seq,k):  (k>>7)*2048 + ((k>>4)&1)*1024 + ((k>>5)&3)*256 + seq*16 + (k&15)
//   x byte(seq,kx): 4096 + (kx>>5)*512 + ((kx>>3)&3)*128 + seq*8 + (kx&7)
// Per step: 8 MX + 16 fp8 MFMA per wave -> wave-local LDS transpose (lanes<16 hold
// all 4 seqs x 16 hu x 4 gates) -> 1 LSTM cell per thread (all 64 lanes) ->
// h fp8 byte to next A buffer + bf16 to lstm_out. One barrier per step.
__global__ __launch_bounds__(1024)
void lstm_scan(const int* __restrict__ sent, const unsigned char* __restrict__ emb8,
               const i32x8* __restrict__ wmx, const long* __restrict__ wx,
               const float* __restrict__ bias, unsigned short* __restrict__ lstm_out) {
  __shared__ long wih_lds[8192];                          // 64 KB (W_ih kk2-3)
  __shared__ __align__(16) unsigned char A_lds[2][6144];  // 12 KB
  __shared__ __align__(8) float redist[16][16][18];       // 18 KB, pad-18: 2-way banks (free)
  __shared__ int idx_lds[2][4];

  const int tid = threadIdx.x;
  const int lane = tid & 63;
  const int w = tid >> 6;
  const int b0 = blockIdx.x << 2;  // 4 seqs per block

  // W_hh MX fragments: [T][q], 8 VGPRs each
  i32x8 whh[2][4];
#pragma unroll
  for (int q = 0; q < 4; ++q)
#pragma unroll
    for (int T = 0; T < 2; ++T)
      whh[T][q] = wmx[((w * 4 + q) * 2 + T) * 64 + lane];

  // W_ih kk0-1 in regs
  long wih2[4][2];
#pragma unroll
  for (int q = 0; q < 4; ++q)
#pragma unroll
    for (int kk = 0; kk < 2; ++kk)
      wih2[q][kk] = wx[((w * 4 + q) * 4 + kk) * 64 + lane];

  // W_ih kk2-3 to LDS
  for (int i = tid; i < 8192; i += 1024) {
    const int l = i & 63, r1 = i >> 6;
    const int kk2 = r1 & 1, q = (r1 >> 1) & 3, w2 = r1 >> 3;
    wih_lds[i] = wx[((w2 * 4 + q) * 4 + 2 + kk2) * 64 + l];
  }
  // per-thread cell bias: gate q of hu = w*16 + (lane&15)
  float bq[4];
#pragma unroll
  for (int q = 0; q < 4; ++q) bq[q] = bias[w * 64 + q * 16 + (lane & 15)];

  // zero BOTH A buffers fully (h rows 4..15 and x rows 4..15 stay zero forever)
  for (int i = tid; i < 3072; i += 1024) ((int*)A_lds)[i] = 0;

  if (tid < 4) {
    idx_lds[0][tid] = sent[(b0 + tid) * TT + 0];
    idx_lds[1][tid] = sent[(b0 + tid) * TT + 1];
  }
  __syncthreads();

  if (tid < 64) {  // gather x(0): seq = tid&3, ch = tid>>2 (16 chunks of 8B)
    const int seq = tid & 3, ch = tid >> 2;
    const int idx = idx_lds[0][seq];
    const u32x2 xr = *(const u32x2*)(emb8 + (size_t)idx * EE + ch * 8);
    *(u32x2*)(&A_lds[0][4096 + (ch >> 2) * 512 + (ch & 3) * 128 + seq * 8]) = xr;
  }
  __syncthreads();

  float cs = 0.f;
  const float S = 1.f / 1024.f;
  // h-write byte address = cw + lane (derivation: hu = w*16+(lane&15), seq = lane>>4)
  const int cw = ((w >> 3) << 11) + ((w & 1) << 10) + (((w >> 1) & 3) << 8);
  const long ob = ((long)(b0 + (lane >> 4)) * TT) * HH + w * 16 + (lane & 15);

#pragma unroll 1
  for (int t = 0; t < TT; ++t) {
    const int p = (t + 1) & 1;
    if (tid < 4 && t + 2 < TT)
      idx_lds[t & 1][tid] = sent[(b0 + tid) * TT + t + 2];

    // gather emb fp8 row for t+1 (latency hidden under MFMA)
    u32x2 xr;
    const bool dog = (tid < 64) && (t + 1 < TT);
    if (dog) {
      const int idx = idx_lds[(t + 1) & 1][tid & 3];
      xr = *(const u32x2*)(emb8 + (size_t)idx * EE + (tid >> 2) * 8);
    }

    const unsigned char* Ah = A_lds[t & 1];
    const long* Ab = (const long*)(A_lds[t & 1]);
    f32x4 ac[4];
#pragma unroll
    for (int q = 0; q < 4; ++q) ac[q] = (f32x4){0.f, 0.f, 0.f, 0.f};

    // h-part: 2 MX tiles (K=128 each)
#pragma unroll
    for (int T = 0; T < 2; ++T) {
      const u32x4 alo = *(const u32x4*)(Ah + T * 2048 + lane * 16);
      const u32x4 ahi = *(const u32x4*)(Ah + T * 2048 + 1024 + lane * 16);
      i32x8 a;
      a[0] = alo[0]; a[1] = alo[1]; a[2] = alo[2]; a[3] = alo[3];
      a[4] = ahi[0]; a[5] = ahi[1]; a[6] = ahi[2]; a[7] = ahi[3];
#pragma unroll
      for (int q = 0; q < 4; ++q) ac[q] = mfma_mx(a, whh[T][q], ac[q]);
    }
    // x-part: 4 fp8 16x16x32 K-tiles; kk0-1 B from regs, kk2-3 B from LDS
#pragma unroll
    for (int kk = 0; kk < 2; ++kk) {
      const long a = Ab[(8 + kk) * 64 + lane];
#pragma unroll
      for (int q = 0; q < 4; ++q) ac[q] = mfma8(a, wih2[q][kk], ac[q]);
    }
#pragma unroll
    for (int kk = 0; kk < 2; ++kk) {
      const long a = Ab[(10 + kk) * 64 + lane];
#pragma unroll
      for (int q = 0; q < 4; ++q) {
        const long b = wih_lds[((w * 4 + q) * 2 + kk) * 64 + lane];
        ac[q] = mfma8(a, b, ac[q]);
      }
    }

    if (dog)  // stash x(t+1) into next A buffer (disjoint from current reads)
      *(u32x2*)(&A_lds[p][4096 + ((tid >> 2) >> 2) * 512 + ((tid >> 2) & 3) * 128 + (tid & 3) * 8]) = xr;

    // wave-local transpose: lanes<16 hold ac[q][r] = gate q, hu_l=lane, seq=r.
    // Scatter so every lane owns one cell (hu_l = lane&15, seq = lane>>4).
    if (lane < 16) {
#pragma unroll
      for (int q = 0; q < 4; ++q) {
        float* pz = &redist[w][lane][q * 4];
        *(f32x2*)pz = (f32x2){ac[q][0], ac[q][1]};
        *(f32x2*)(pz + 2) = (f32x2){ac[q][2], ac[q][3]};
      }
    }
    asm volatile("s_waitcnt lgkmcnt(0)" ::: "memory");
    __builtin_amdgcn_sched_barrier(0);
    float g4[4];
#pragma unroll
    for (int q = 0; q < 4; ++q)
      g4[q] = redist[w][lane & 15][q * 4 + (lane >> 4)];

    // LSTM cell: one (hu, seq) per thread
    const float gi = g4[0] * S + bq[0];
    const float gf = g4[1] * S + bq[1];
    const float gg = g4[2] * S + bq[2];
    const float go = g4[3] * S + bq[3];
    cs = sigm(gf) * cs + sigm(gi) * tanhf_(gg);
    const float hv = sigm(go) * tanhf_(cs);

    // h(t+1) fp8 x16 into next A buffer; bf16 to global lstm_out
    const int pk = __builtin_amdgcn_cvt_pk_fp8_f32(16.f * hv, 0.f, 0, false);
    A_lds[p][cw + lane] = (unsigned char)(pk & 0xff);
    lstm_out[ob + (long)t * HH] = to_bf16(hv);

    __syncthreads();
  }
}

// ---------------- logits = lstm_out @ W_lin^T + b_lin ----------------
__global__ __launch_bounds__(256)
void logits_gemm(const unsigned short* __restrict__ lstm, const unsigned short* __restrict__ wl,
                 const float* __restrict__ blin, float* __restrict__ logits) {
  const int tid = threadIdx.x, l = tid & 63, wv = tid >> 6;
  const long m0 = (long)blockIdx.x * 64 + wv * 16;
  f32x4 ac[4];
#pragma unroll
  for (int q = 0; q < 4; ++q) ac[q] = (f32x4){0.f, 0.f, 0.f, 0.f};
  const unsigned short* arow = lstm + (m0 + (l & 15)) * HH + ((l >> 4) << 3);
#pragma unroll
  for (int kk = 0; kk < 8; ++kk) {
    const bf16x8_t a = __builtin_bit_cast(bf16x8_t, *(const u32x4*)(arow + kk * 32));
#pragma unroll
    for (int q = 0; q < 4; ++q) {
      const bf16x8_t b = __builtin_bit_cast(bf16x8_t, *(const u32x4*)(wl + (((q * 8 + kk) * 64 + l) << 3)));
      ac[q] = __builtin_amdgcn_mfma_f32_16x16x32_bf16(a, b, ac[q], 0, 0, 0);
    }
  }
  const int r0 = (l >> 4) << 2;
#pragma unroll
  for (int q = 0; q < 4; ++q) {
    const int col = q * 16 + (l & 15);
    const float bb = blin[col];
#pragma unroll
    for (int r = 0; r < 4; ++r)
      logits[(m0 + r0 + r) * CC + col] = ac[q][r] + bb;
  }
}

// ------------- log_softmax over time + product over time, per (b,c) -------------
// True product overflows fp32/fp64 (ref = +inf). Accumulate log2|logp| and emit
// exp2(min(sum,127)): exact when representable, finite otherwise (never inf/nan).
__global__ __launch_bounds__(256)
void softmax_prod(const float* __restrict__ logits, float* __restrict__ out) {
  __shared__ float lds[TT * CC];   // 128 KB
  __shared__ float red[3][4][CC];
  const int tid = threadIdx.x, b = blockIdx.x;
  const f32x4* src = (const f32x4*)(logits + (long)b * TT * CC);
  f32x4* dst = (f32x4*)lds;
#pragma unroll 1
  for (int i = tid; i < TT * CC / 4; i += 256) dst[i] = src[i];
  __syncthreads();

  const int c = tid & 63, part = tid >> 6;
  const int t0 = part * 128;
  float m = -3.0e38f;
  for (int k = 0; k < 128; ++k) m = fmaxf(m, lds[(t0 + k) * CC + c]);
  red[0][part][c] = m;
  __syncthreads();
  m = fmaxf(fmaxf(red[0][0][c], red[0][1][c]), fmaxf(red[0][2][c], red[0][3][c]));

  float ssum = 0.f;
  for (int k = 0; k < 128; ++k) ssum += __expf(lds[(t0 + k) * CC + c] - m);
  red[1][part][c] = ssum;
  __syncthreads();
  ssum = red[1][0][c] + red[1][1][c] + red[1][2][c] + red[1][3][c];
  const float lse = m + __logf(ssum);

  float pacc = 0.f;
  for (int k = 0; k < 128; ++k) pacc += __log2f(fabsf(lds[(t0 + k) * CC + c] - lse));
  red[2][part][c] = pacc;
  __syncthreads();
  if (part == 0) {
    const float tot = red[2][0][c] + red[2][1][c] + red[2][2][c] + red[2][3][c];
    out[b * CC + c] = exp2f(fminf(tot, 127.0f));
  }
}

extern "C" void kernel_launch(void* const* d_in, const int* in_sizes, int n_in,
                              void* d_out, int out_size, void* d_ws, size_t ws_size,
                              hipStream_t stream) {
  (void)in_sizes; (void)n_in; (void)out_size;
  if (ws_size < WS_NEED) return;  // produces 0-node graph -> explicit harness error

  const int*   sent = (const int*)d_in[0];
  const float* emb  = (const float*)d_in[1];
  const float* Wih  = (const float*)d_in[2];
  const float* Whh  = (const float*)d_in[3];
  const float* bih  = (const float*)d_in[4];
  const float* bhh  = (const float*)d_in[5];
  const float* Wlin = (const float*)d_in[6];
  const float* blin = (const float*)d_in[7];
  float* out = (float*)d_out;
  char* ws = (char*)d_ws;

  unsigned char*  emb8 = (unsigned char*)(ws + OFF_EMB);
  unsigned char*  wmx  = (unsigned char*)(ws + OFF_WMX);
  unsigned char*  wxp  = (unsigned char*)(ws + OFF_WX);
  float*          bp   = (float*)(ws + OFF_BIAS);
  unsigned short* wl   = (unsigned short*)(ws + OFF_WLIN);
  unsigned short* lo   = (unsigned short*)(ws + OFF_LSTM);
  float*          lg   = (float*)(ws + OFF_LOG);

  prep_emb<<<1024, 256, 0, stream>>>(emb, (unsigned*)emb8);
  prep_wmx<<<1024, 256, 0, stream>>>(Whh, wmx);
  prep_wx<<<512, 256, 0, stream>>>(Wih, wxp);
  prep_bias<<<4, 256, 0, stream>>>(bih, bhh, bp);
  prep_wlin<<<64, 256, 0, stream>>>(Wlin, wl);
  lstm_scan<<<64, 1024, 0, stream>>>(sent, emb8, (const i32x8*)wmx, (const long*)wxp, bp, lo);
  logits_gemm<<<2048, 256, 0, stream>>>(lo, wl, blin, lg);
  softmax_prod<<<256, 256, 0, stream>>>(lg, out);
}

// Round 6
// 960.230 us; speedup vs baseline: 1.4450x; 1.4450x over previous
//
#include <hip/hip_runtime.h>

#define TT 512
#define HH 256
#define EE 128
#define BB 256
#define CC 64
#define VV 50000

// workspace offsets (bytes), all 256-aligned
#define OFF_EMB   0ull           // 50000*128       = 6,400,000   (emb as fp8)
#define OFF_WHA   6400000ull     // 8*8*2*2048      =   262,144   (W_hh MX A-frags)
#define OFF_WXA   6662144ull     // 8*8*2048        =   131,072   (W_ih MX A-frags)
#define OFF_BIAS  6793216ull     // 1024*4          =     4,096   (pre-scaled biases)
#define OFF_WLIN  6797312ull     // 4*8*64*8*2      =    16,384   (W_lin bf16 frags)
#define OFF_LSTM  6813696ull     // 256*512*256*2   = 67,108,864  (lstm_out bf16)
#define OFF_LOG   73922560ull    // 256*512*64*4    = 33,554,432  (logits f32)
#define WS_NEED   107476992ull

typedef __attribute__((ext_vector_type(4))) float    f32x4;
typedef __attribute__((ext_vector_type(4))) unsigned u32x4;
typedef __attribute__((ext_vector_type(2))) unsigned u32x2;
typedef __attribute__((ext_vector_type(8))) int      i32x8;
typedef __bf16 bf16x8_t __attribute__((ext_vector_type(8)));

__device__ __forceinline__ float rcp_f(float x) { return __builtin_amdgcn_rcpf(x); }
__device__ __forceinline__ float exp2_(float x) {
  float r; asm("v_exp_f32 %0, %1" : "=v"(r) : "v"(x)); return r;
}
__device__ __forceinline__ unsigned short to_bf16(float f) {
  unsigned u = __float_as_uint(f);
  return (unsigned short)((u + 0x7fffu + ((u >> 16) & 1u)) >> 16);
}
// MX-scaled fp8 GEMM, K=128, all scale exponents = 127 (x1.0) -> plain fp8 at 2x rate
__device__ __forceinline__ f32x4 mfma_mx(i32x8 a, i32x8 b, f32x4 c) {
  return __builtin_amdgcn_mfma_scale_f32_16x16x128_f8f6f4(
      a, b, c, 0, 0, 0, 0x7f7f7f7f, 0, 0x7f7f7f7f);
}

#define LOG2E  1.442695041f
#define SN_    (-LOG2E / 1024.f)
#define SG_    (-2.f * LOG2E / 1024.f)
#define C2_    (-2.f * LOG2E)

// ---------------- prep: emb fp32 -> fp8 e4m3 (unscaled) ----------------
__global__ void prep_emb(const float* __restrict__ emb, unsigned* __restrict__ out) {
  const int stride = gridDim.x * blockDim.x;
  for (int u = blockIdx.x * blockDim.x + threadIdx.x; u < (VV * EE / 4); u += stride) {
    const f32x4 f = ((const f32x4*)emb)[u];
    int r = __builtin_amdgcn_cvt_pk_fp8_f32(f[0], f[1], 0, false);
    r = __builtin_amdgcn_cvt_pk_fp8_f32(f[2], f[3], r, true);
    out[u] = (unsigned)r;
  }
}

// ------- prep: W_hh*64 -> MX A-fragments (A = weights, M-rows = hu_l*4+gate) -------
// id = (((w8*8+mt)*2+kt)*64 + l)*32 + j ; lane l: row l&15, k = kt*128 + (l>>4)*32 + j
__global__ void prep_wha(const float* __restrict__ Whh, unsigned char* __restrict__ wf) {
  const int id = blockIdx.x * 256 + threadIdx.x;  // exactly 262144 threads
  const int j = id & 31, l = (id >> 5) & 63;
  const int kt = (id >> 11) & 1, mt = (id >> 12) & 7, w8 = id >> 15;
  const int r16 = l & 15, q = r16 & 3, hul = r16 >> 2;
  const int grow = q * 256 + (w8 * 32 + mt * 4 + hul);
  const int k = kt * 128 + ((l >> 4) << 5) + j;
  const int r = __builtin_amdgcn_cvt_pk_fp8_f32(64.f * Whh[grow * HH + k], 0.f, 0, false);
  wf[id] = (unsigned char)(r & 0xff);
}

// ------- prep: W_ih*1024 -> MX A-fragments, [w8][mt][kg][half][row][16B] layout -------
__global__ void prep_wxa(const float* __restrict__ Wih, unsigned char* __restrict__ wf) {
  const int id = blockIdx.x * 256 + threadIdx.x;  // exactly 131072 threads
  const int b = id & 15, row = (id >> 4) & 15;
  const int half = (id >> 8) & 1, kg = (id >> 9) & 3, mt = (id >> 11) & 7, w8 = id >> 14;
  const int q = row & 3, hul = row >> 2;
  const int grow = q * 256 + (w8 * 32 + mt * 4 + hul);
  const int k = kg * 32 + half * 16 + b;  // 0..127
  const int r = __builtin_amdgcn_cvt_pk_fp8_f32(1024.f * Wih[grow * EE + k], 0.f, 0, false);
  wf[id] = (unsigned char)(r & 0xff);
}

// bias pre-scaled for exp2-based activations: gates i,f,o: -log2e*(bih+bhh); gate g: -2log2e*(...)
__global__ void prep_bias(const float* __restrict__ bih, const float* __restrict__ bhh,
                          float* __restrict__ bp) {
  const int n = blockIdx.x * 256 + threadIdx.x;  // 1024 threads, [gate][hu] original order
  const float sc = (n >= 512 && n < 768) ? (-2.f * LOG2E) : (-LOG2E);
  bp[n] = (bih[n] + bhh[n]) * sc;
}

__global__ void prep_wlin(const float* __restrict__ Wlin, unsigned short* __restrict__ wl) {
  const int id = blockIdx.x * 256 + threadIdx.x;  // 16384 threads
  const int j = id & 7, l = (id >> 3) & 63;
  const int kk = (id >> 9) & 7, q = id >> 12;
  const int c = q * 16 + (l & 15);
  const int k = kk * 32 + ((l >> 4) << 3) + j;
  wl[id] = to_bf16(Wlin[c * HH + k]);
}

// ---------------- persistent LSTM scan: 64 blocks x 512 thr (8 waves), 4 seqs/block ----------
// Swapped operands: A = weights (M = gate-rows, per wave 8 M-tiles), B = activations
// (N = 16 cols, seqs 0-3 real). B buffer (double, 6144 B): per K-tile kt:
//   byte(col=seq, k) at kt*2048 + ((k&127)>>5)*512 + ((k>>4)&1)*256 + seq*16 + (k&15)
// C/D: lane l = (col seq = l&15, rows hu_l*4+gate) -> acc[mt] f32x4 = one cell's 4 gates.
// Redistribute via per-wave LDS (8 b128 writes by 16 lanes, 2 b128 reads) -> 2 cells/lane.
// Raw s_barrier + lgkmcnt(0) only (no vmcnt drain; lstm_out stores fly un-acked).
__global__ __launch_bounds__(512, 2)
void lstm_scan(const int* __restrict__ sent, const unsigned char* __restrict__ emb8,
               const unsigned char* __restrict__ wha, const unsigned char* __restrict__ wxa,
               const float* __restrict__ bias, unsigned short* __restrict__ lstm_out) {
  __shared__ u32x4 xa16[4096];                  // 64 KB: W_ih A-frags, tiles 4..7 per wave
  __shared__ __align__(16) u32x4 act16[2][384]; // 12 KB: B activations, double-buffered
  __shared__ __align__(16) float redist[8][8][4][4][4];  // 16 KB
  __shared__ int sent_lds[4][512];              // 8 KB

  const int tid = threadIdx.x;
  const int lane = tid & 63;
  const int w = tid >> 6;          // wave 0..7
  const int b0 = blockIdx.x << 2;  // 4 seqs per block

  // ---- one-time staging ----
  // W_hh A-frags: 8 M-tiles x 2 K-tiles in registers (128 VGPR)
  i32x8 Ah[8][2];
#pragma unroll
  for (int mt = 0; mt < 8; ++mt)
#pragma unroll
    for (int kt = 0; kt < 2; ++kt)
      Ah[mt][kt] = *(const i32x8*)(wha + ((w * 8 + mt) * 2 + kt) * 2048 + lane * 32);

  // W_ih A-frags tiles 0..3 in registers (32 VGPR)
  const int fo = ((lane >> 4) << 9) + ((lane & 15) << 4);
  i32x8 Ax[4];
#pragma unroll
  for (int mt = 0; mt < 4; ++mt) {
    const u32x4 lo = *(const u32x4*)(wxa + (w * 8 + mt) * 2048 + fo);
    const u32x4 hi = *(const u32x4*)(wxa + (w * 8 + mt) * 2048 + fo + 256);
    i32x8 a;
    a[0] = lo[0]; a[1] = lo[1]; a[2] = lo[2]; a[3] = lo[3];
    a[4] = hi[0]; a[5] = hi[1]; a[6] = hi[2]; a[7] = hi[3];
    Ax[mt] = a;
  }
  // W_ih tiles 4..7 (all waves) -> LDS
  for (int c = tid; c < 4096; c += 512) {
    const int w8g = c >> 9, rem = c & 511;
    const int mt = 4 + (rem >> 7), inner = rem & 127;
    xa16[c] = *(const u32x4*)(wxa + (w8g * 8 + mt) * 2048 + inner * 16);
  }
  // whole sentence slice -> LDS
  for (int i = tid; i < 2048; i += 512)
    sent_lds[i >> 9][i & 511] = sent[(b0 + (i >> 9)) * TT + (i & 511)];
  // zero both B buffers
  for (int i = tid; i < 768; i += 512) ((u32x4*)act16)[i] = (u32x4){0, 0, 0, 0};

  // per-lane cell geometry: s = l&3, hul = l>>4, d = (l>>2)&3 -> tiles 2d, 2d+1
  const int s = lane & 3, hul = lane >> 4, d = (lane >> 2) & 3;
  const int mt0 = 2 * d, mt1 = 2 * d + 1;
  const int hu0 = w * 32 + mt0 * 4 + hul;
  const int hu1 = w * 32 + mt1 * 4 + hul;
  const float b00 = bias[0 * 256 + hu0], b01 = bias[1 * 256 + hu0],
              b02 = bias[2 * 256 + hu0], b03 = bias[3 * 256 + hu0];
  const float b10 = bias[0 * 256 + hu1], b11 = bias[1 * 256 + hu1],
              b12 = bias[2 * 256 + hu1], b13 = bias[3 * 256 + hu1];
  const int hb0 = ((hu0 >> 7) << 11) + (((hu0 >> 5) & 3) << 9) + (((hu0 >> 4) & 1) << 8) + (s << 4) + (hu0 & 15);
  const int hb1 = ((hu1 >> 7) << 11) + (((hu1 >> 5) & 3) << 9) + (((hu1 >> 4) & 1) << 8) + (s << 4) + (hu1 & 15);
  const long ob0 = ((long)(b0 + s) * TT) * HH + hu0;
  const long ob1 = ((long)(b0 + s) * TT) * HH + hu1;
  const int gseq = lane & 3, gch = w * 2 + ((lane >> 2) & 1);  // gatherer mapping (lane<8)
  const int gw = 4096 + ((gch >> 2) << 9) + (((gch >> 1) & 1) << 8) + (gseq << 4) + ((gch & 1) << 3);

  __syncthreads();

  // gather x(0) into buffer 0
  if (lane < 8) {
    const int idx = sent_lds[gseq][0];
    const u32x2 xr = *(const u32x2*)(emb8 + (size_t)idx * EE + gch * 8);
    *(u32x2*)((unsigned char*)&act16[0][0] + gw) = xr;
  }
  __syncthreads();

  float cs0 = 0.f, cs1 = 0.f;

#pragma unroll 1
  for (int t = 0; t < TT; ++t) {
    const int cur = t & 1, nxt = cur ^ 1;
    unsigned char* Anb = (unsigned char*)&act16[nxt][0];

    // issue emb gather for t+1 early (latency hidden under MFMA)
    u32x2 xr;
    const bool dog = (lane < 8) && (t + 1 < TT);
    if (dog) {
      const int idx = sent_lds[gseq][t + 1];
      xr = *(const u32x2*)(emb8 + (size_t)idx * EE + gch * 8);
    }

    // ---- MFMA: 8 M-tiles x 3 K-tiles, all MX ----
    f32x4 acc[8];
#pragma unroll
    for (int mt = 0; mt < 8; ++mt) acc[mt] = (f32x4){0.f, 0.f, 0.f, 0.f};

    const int i0 = ((lane >> 4) << 5) + (lane & 15);
#pragma unroll
    for (int kt = 0; kt < 2; ++kt) {  // h K-tiles (weights in regs)
      const u32x4 lo = act16[cur][kt * 128 + i0];
      const u32x4 hi = act16[cur][kt * 128 + i0 + 16];
      i32x8 B;
      B[0] = lo[0]; B[1] = lo[1]; B[2] = lo[2]; B[3] = lo[3];
      B[4] = hi[0]; B[5] = hi[1]; B[6] = hi[2]; B[7] = hi[3];
#pragma unroll
      for (int mt = 0; mt < 8; ++mt) acc[mt] = mfma_mx(Ah[mt][kt], B, acc[mt]);
    }
    {  // x K-tile
      const u32x4 lo = act16[cur][256 + i0];
      const u32x4 hi = act16[cur][256 + i0 + 16];
      i32x8 B;
      B[0] = lo[0]; B[1] = lo[1]; B[2] = lo[2]; B[3] = lo[3];
      B[4] = hi[0]; B[5] = hi[1]; B[6] = hi[2]; B[7] = hi[3];
#pragma unroll
      for (int mt = 0; mt < 4; ++mt) acc[mt] = mfma_mx(Ax[mt], B, acc[mt]);
#pragma unroll
      for (int mt = 4; mt < 8; ++mt) {  // weights from LDS
        const int tb = (w * 4 + (mt - 4)) * 128 + ((lane >> 4) << 5) + (lane & 15);
        const u32x4 alo = xa16[tb];
        const u32x4 ahi = xa16[tb + 16];
        i32x8 a;
        a[0] = alo[0]; a[1] = alo[1]; a[2] = alo[2]; a[3] = alo[3];
        a[4] = ahi[0]; a[5] = ahi[1]; a[6] = ahi[2]; a[7] = ahi[3];
        acc[mt] = mfma_mx(a, B, acc[mt]);
      }
    }

    // stash x(t+1) into next buffer (disjoint from current reads)
    if (dog) *(u32x2*)(Anb + gw) = xr;

    // ---- redistribute: cols 0-3 lanes hold complete cells; spread to all 64 lanes ----
    if ((lane & 15) < 4) {
#pragma unroll
      for (int mt = 0; mt < 8; ++mt)
        *(f32x4*)&redist[w][mt][hul][lane & 3][0] = acc[mt];
    }
    asm volatile("s_waitcnt lgkmcnt(0)" ::: "memory");
    __builtin_amdgcn_sched_barrier(0);
    const f32x4 g0 = *(const f32x4*)&redist[w][mt0][hul][s][0];
    const f32x4 g1 = *(const f32x4*)&redist[w][mt1][hul][s][0];

    // ---- 2 LSTM cells per thread (exp2-folded) ----
    float si, sf, so, tg, tc, hv0, hv1;
    si = rcp_f(1.f + exp2_(g0[0] * SN_ + b00));
    sf = rcp_f(1.f + exp2_(g0[1] * SN_ + b01));
    tg = 2.f * rcp_f(1.f + exp2_(g0[2] * SG_ + b02)) - 1.f;
    so = rcp_f(1.f + exp2_(g0[3] * SN_ + b03));
    cs0 = sf * cs0 + si * tg;
    tc = 2.f * rcp_f(1.f + exp2_(cs0 * C2_)) - 1.f;
    hv0 = so * tc;
    si = rcp_f(1.f + exp2_(g1[0] * SN_ + b10));
    sf = rcp_f(1.f + exp2_(g1[1] * SN_ + b11));
    tg = 2.f * rcp_f(1.f + exp2_(g1[2] * SG_ + b12)) - 1.f;
    so = rcp_f(1.f + exp2_(g1[3] * SN_ + b13));
    cs1 = sf * cs1 + si * tg;
    tc = 2.f * rcp_f(1.f + exp2_(cs1 * C2_)) - 1.f;
    hv1 = so * tc;

    // h(t+1) fp8 x16 into next B buffer; bf16 to global (un-drained)
    const int pk = __builtin_amdgcn_cvt_pk_fp8_f32(16.f * hv0, 16.f * hv1, 0, false);
    Anb[hb0] = (unsigned char)(pk & 0xff);
    Anb[hb1] = (unsigned char)((pk >> 8) & 0xff);
    lstm_out[ob0 + (long)t * HH] = to_bf16(hv0);
    lstm_out[ob1 + (long)t * HH] = to_bf16(hv1);

    // barrier WITHOUT vmcnt drain: LDS visibility only
    asm volatile("s_waitcnt lgkmcnt(0)" ::: "memory");
    __builtin_amdgcn_s_barrier();
  }
}

// ---------------- logits = lstm_out @ W_lin^T + b_lin ----------------
__global__ __launch_bounds__(256)
void logits_gemm(const unsigned short* __restrict__ lstm, const unsigned short* __restrict__ wl,
                 const float* __restrict__ blin, float* __restrict__ logits) {
  const int tid = threadIdx.x, l = tid & 63, wv = tid >> 6;
  const long m0 = (long)blockIdx.x * 64 + wv * 16;
  f32x4 ac[4];
#pragma unroll
  for (int q = 0; q < 4; ++q) ac[q] = (f32x4){0.f, 0.f, 0.f, 0.f};
  const unsigned short* arow = lstm + (m0 + (l & 15)) * HH + ((l >> 4) << 3);
#pragma unroll
  for (int kk = 0; kk < 8; ++kk) {
    const bf16x8_t a = __builtin_bit_cast(bf16x8_t, *(const u32x4*)(arow + kk * 32));
#pragma unroll
    for (int q = 0; q < 4; ++q) {
      const bf16x8_t b = __builtin_bit_cast(bf16x8_t, *(const u32x4*)(wl + (((q * 8 + kk) * 64 + l) << 3)));
      ac[q] = __builtin_amdgcn_mfma_f32_16x16x32_bf16(a, b, ac[q], 0, 0, 0);
    }
  }
  const int r0 = (l >> 4) << 2;
#pragma unroll
  for (int q = 0; q < 4; ++q) {
    const int col = q * 16 + (l & 15);
    const float bb = blin[col];
#pragma unroll
    for (int r = 0; r < 4; ++r)
      logits[(m0 + r0 + r) * CC + col] = ac[q][r] + bb;
  }
}

// ------------- log_softmax over time + product over time, per (b,c) -------------
// True product overflows fp32/fp64 (ref = +inf). Accumulate log2|logp| and emit
// exp2(min(sum,127)): exact when representable, finite otherwise (never inf/nan).
__global__ __launch_bounds__(256)
void softmax_prod(const float* __restrict__ logits, float* __restrict__ out) {
  __shared__ float lds[TT * CC];   // 128 KB
  __shared__ float red[3][4][CC];
  const int tid = threadIdx.x, b = blockIdx.x;
  const f32x4* src = (const f32x4*)(logits + (long)b * TT * CC);
  f32x4* dst = (f32x4*)lds;
#pragma unroll 1
  for (int i = tid; i < TT * CC / 4; i += 256) dst[i] = src[i];
  __syncthreads();

  const int c = tid & 63, part = tid >> 6;
  const int t0 = part * 128;
  float m = -3.0e38f;
  for (int k = 0; k < 128; ++k) m = fmaxf(m, lds[(t0 + k) * CC + c]);
  red[0][part][c] = m;
  __syncthreads();
  m = fmaxf(fmaxf(red[0][0][c], red[0][1][c]), fmaxf(red[0][2][c], red[0][3][c]));

  float ssum = 0.f;
  for (int k = 0; k < 128; ++k) ssum += __expf(lds[(t0 + k) * CC + c] - m);
  red[1][part][c] = ssum;
  __syncthreads();
  ssum = red[1][0][c] + red[1][1][c] + red[1][2][c] + red[1][3][c];
  const float lse = m + __logf(ssum);

  float pacc = 0.f;
  for (int k = 0; k < 128; ++k) pacc += __log2f(fabsf(lds[(t0 + k) * CC + c] - lse));
  red[2][part][c] = pacc;
  __syncthreads();
  if (part == 0) {
    const float tot = red[2][0][c] + red[2][1][c] + red[2][2][c] + red[2][3][c];
    out[b * CC + c] = exp2f(fminf(tot, 127.0f));
  }
}

extern "C" void kernel_launch(void* const* d_in, const int* in_sizes, int n_in,
                              void* d_out, int out_size, void* d_ws, size_t ws_size,
                              hipStream_t stream) {
  (void)in_sizes; (void)n_in; (void)out_size;
  if (ws_size < WS_NEED) return;  // produces 0-node graph -> explicit harness error

  const int*   sent = (const int*)d_in[0];
  const float* emb  = (const float*)d_in[1];
  const float* Wih  = (const float*)d_in[2];
  const float* Whh  = (const float*)d_in[3];
  const float* bih  = (const float*)d_in[4];
  const float* bhh  = (const float*)d_in[5];
  const float* Wlin = (const float*)d_in[6];
  const float* blin = (const float*)d_in[7];
  float* out = (float*)d_out;
  char* ws = (char*)d_ws;

  unsigned char*  emb8 = (unsigned char*)(ws + OFF_EMB);
  unsigned char*  wha  = (unsigned char*)(ws + OFF_WHA);
  unsigned char*  wxa  = (unsigned char*)(ws + OFF_WXA);
  float*          bp   = (float*)(ws + OFF_BIAS);
  unsigned short* wl   = (unsigned short*)(ws + OFF_WLIN);
  unsigned short* lo   = (unsigned short*)(ws + OFF_LSTM);
  float*          lg   = (float*)(ws + OFF_LOG);

  prep_emb<<<1024, 256, 0, stream>>>(emb, (unsigned*)emb8);
  prep_wha<<<1024, 256, 0, stream>>>(Whh, wha);
  prep_wxa<<<512, 256, 0, stream>>>(Wih, wxa);
  prep_bias<<<4, 256, 0, stream>>>(bih, bhh, bp);
  prep_wlin<<<64, 256, 0, stream>>>(Wlin, wl);
  lstm_scan<<<64, 512, 0, stream>>>(sent, emb8, wha, wxa, bp, lo);
  logits_gemm<<<2048, 256, 0, stream>>>(lo, wl, blin, lg);
  softmax_prod<<<256, 256, 0, stream>>>(lg, out);
}

// Round 7
// 826.642 us; speedup vs baseline: 1.6785x; 1.1616x over previous
//
#include <hip/hip_runtime.h>

#define TT 512
#define HH 256
#define EE 128
#define BB 256
#define CC 64
#define VV 50000

// workspace offsets (bytes), all 256-aligned
#define OFF_EMB   0ull           // 50000*128       = 6,400,000   (emb as fp8)
#define OFF_WHA   6400000ull     // 8*8*2*2048      =   262,144   (W_hh MX A-frags)
#define OFF_WXA   6662144ull     // 8*8*2048        =   131,072   (W_ih MX A-frags)
#define OFF_BIAS  6793216ull     // 1024*4          =     4,096   (pre-scaled biases)
#define OFF_WLIN  6797312ull     // 4*8*64*8*2      =    16,384   (W_lin bf16 frags)
#define OFF_LSTM  6813696ull     // 256*512*256*2   = 67,108,864  (lstm_out bf16)
#define OFF_LOG   73922560ull    // 256*512*64*4    = 33,554,432  (logits f32)
#define WS_NEED   107476992ull

typedef __attribute__((ext_vector_type(4))) float    f32x4;
typedef __attribute__((ext_vector_type(4))) unsigned u32x4;
typedef __attribute__((ext_vector_type(2))) unsigned u32x2;
typedef __attribute__((ext_vector_type(8))) int      i32x8;
typedef __bf16 bf16x8_t __attribute__((ext_vector_type(8)));

__device__ __forceinline__ float rcp_f(float x) { return __builtin_amdgcn_rcpf(x); }
__device__ __forceinline__ float exp2_(float x) {
  float r; asm("v_exp_f32 %0, %1" : "=v"(r) : "v"(x)); return r;
}
__device__ __forceinline__ unsigned short to_bf16(float f) {
  unsigned u = __float_as_uint(f);
  return (unsigned short)((u + 0x7fffu + ((u >> 16) & 1u)) >> 16);
}
// MX-scaled fp8 GEMM, K=128, all scale exponents = 127 (x1.0) -> plain fp8 at 2x rate
__device__ __forceinline__ f32x4 mfma_mx(i32x8 a, i32x8 b, f32x4 c) {
  return __builtin_amdgcn_mfma_scale_f32_16x16x128_f8f6f4(
      a, b, c, 0, 0, 0, 0x7f7f7f7f, 0, 0x7f7f7f7f);
}
__device__ __forceinline__ i32x8 pack8(u32x4 lo, u32x4 hi) {
  i32x8 a;
  a[0] = lo[0]; a[1] = lo[1]; a[2] = lo[2]; a[3] = lo[3];
  a[4] = hi[0]; a[5] = hi[1]; a[6] = hi[2]; a[7] = hi[3];
  return a;
}

#define LOG2E  1.442695041f
#define SN_    (-LOG2E / 1024.f)
#define SG_    (-2.f * LOG2E / 1024.f)
#define C2_    (-2.f * LOG2E)

// ---------------- prep: emb fp32 -> fp8 e4m3 (unscaled) ----------------
__global__ void prep_emb(const float* __restrict__ emb, unsigned* __restrict__ out) {
  const int stride = gridDim.x * blockDim.x;
  for (int u = blockIdx.x * blockDim.x + threadIdx.x; u < (VV * EE / 4); u += stride) {
    const f32x4 f = ((const f32x4*)emb)[u];
    int r = __builtin_amdgcn_cvt_pk_fp8_f32(f[0], f[1], 0, false);
    r = __builtin_amdgcn_cvt_pk_fp8_f32(f[2], f[3], r, true);
    out[u] = (unsigned)r;
  }
}

// ------- prep: W_hh*64 -> MX A-fragments (A = weights, M-rows = hu_l*4+gate) -------
__global__ void prep_wha(const float* __restrict__ Whh, unsigned char* __restrict__ wf) {
  const int id = blockIdx.x * 256 + threadIdx.x;  // exactly 262144 threads
  const int j = id & 31, l = (id >> 5) & 63;
  const int kt = (id >> 11) & 1, mt = (id >> 12) & 7, w8 = id >> 15;
  const int r16 = l & 15, q = r16 & 3, hul = r16 >> 2;
  const int grow = q * 256 + (w8 * 32 + mt * 4 + hul);
  const int k = kt * 128 + ((l >> 4) << 5) + j;
  const int r = __builtin_amdgcn_cvt_pk_fp8_f32(64.f * Whh[grow * HH + k], 0.f, 0, false);
  wf[id] = (unsigned char)(r & 0xff);
}

// ------- prep: W_ih*1024 -> MX A-fragments, [w8][mt][kg][half][row][16B] layout -------
__global__ void prep_wxa(const float* __restrict__ Wih, unsigned char* __restrict__ wf) {
  const int id = blockIdx.x * 256 + threadIdx.x;  // exactly 131072 threads
  const int b = id & 15, row = (id >> 4) & 15;
  const int half = (id >> 8) & 1, kg = (id >> 9) & 3, mt = (id >> 11) & 7, w8 = id >> 14;
  const int q = row & 3, hul = row >> 2;
  const int grow = q * 256 + (w8 * 32 + mt * 4 + hul);
  const int k = kg * 32 + half * 16 + b;  // 0..127
  const int r = __builtin_amdgcn_cvt_pk_fp8_f32(1024.f * Wih[grow * EE + k], 0.f, 0, false);
  wf[id] = (unsigned char)(r & 0xff);
}

// bias pre-scaled for exp2-based activations
__global__ void prep_bias(const float* __restrict__ bih, const float* __restrict__ bhh,
                          float* __restrict__ bp) {
  const int n = blockIdx.x * 256 + threadIdx.x;  // 1024 threads, [gate][hu] original order
  const float sc = (n >= 512 && n < 768) ? (-2.f * LOG2E) : (-LOG2E);
  bp[n] = (bih[n] + bhh[n]) * sc;
}

__global__ void prep_wlin(const float* __restrict__ Wlin, unsigned short* __restrict__ wl) {
  const int id = blockIdx.x * 256 + threadIdx.x;  // 16384 threads
  const int j = id & 7, l = (id >> 3) & 63;
  const int kk = (id >> 9) & 7, q = id >> 12;
  const int c = q * 16 + (l & 15);
  const int k = kk * 32 + ((l >> 4) << 3) + j;
  wl[id] = to_bf16(Wlin[c * HH + k]);
}

// ---------------- persistent LSTM scan: 64 blocks x 512 thr (8 waves), 4 seqs/block ----------
// Swapped operands: A = weights, B = activations (N=16 cols, seqs 0-3 real).
// In-step software pipeline:
//   enter step t with acc[] preloaded with x-contrib(t);
//   16 h-MFMAs accumulate on top -> gates(t); redist-write captures acc;
//   8 x-MFMAs re-init acc with x-contrib(t+1) (reads xbuf, written 1 step ago) and
//   drain in the matrix pipe WHILE this wave runs redist-read + activation;
//   emb gather runs at distance 2 (issued at t, stashed end-of-t for use at t+1).
// One raw s_barrier (lgkm only, no vmcnt drain) per step.
__global__ __launch_bounds__(512, 1)
void lstm_scan(const int* __restrict__ sent, const unsigned char* __restrict__ emb8,
               const unsigned char* __restrict__ wha, const unsigned char* __restrict__ wxa,
               const float* __restrict__ bias, unsigned short* __restrict__ lstm_out) {
  __shared__ u32x4 xa16[4096];                   // 64 KB: W_ih A-frags mt4..7, per wave
  __shared__ __align__(16) u32x4 acth[2][256];   // 8 KB: h B-frags, double-buffered
  __shared__ __align__(16) u32x4 xbuf[2][128];   // 4 KB: x B-frags, parity-buffered
  __shared__ __align__(16) float redist[8][8][4][4][4];  // 16 KB
  __shared__ int sent_lds[4][512];               // 8 KB   -> total 100 KB, 1 block/CU

  const int tid = threadIdx.x;
  const int lane = tid & 63;
  const int w = tid >> 6;          // wave 0..7
  const int b0 = blockIdx.x << 2;  // 4 seqs per block

  // ---- one-time staging ----
  i32x8 Ah[8][2];  // W_hh A-frags: 8 M-tiles x 2 K-tiles (128 VGPR)
#pragma unroll
  for (int mt = 0; mt < 8; ++mt)
#pragma unroll
    for (int kt = 0; kt < 2; ++kt)
      Ah[mt][kt] = *(const i32x8*)(wha + ((w * 8 + mt) * 2 + kt) * 2048 + lane * 32);

  const int fo = ((lane >> 4) << 9) + ((lane & 15) << 4);
  i32x8 Ax[4];     // W_ih A-frags tiles 0..3 (32 VGPR)
#pragma unroll
  for (int mt = 0; mt < 4; ++mt)
    Ax[mt] = pack8(*(const u32x4*)(wxa + (w * 8 + mt) * 2048 + fo),
                   *(const u32x4*)(wxa + (w * 8 + mt) * 2048 + fo + 256));

  // W_ih tiles 4..7 (all waves) -> LDS
  for (int c = tid; c < 4096; c += 512) {
    const int w8g = c >> 9, rem = c & 511;
    const int mt = 4 + (rem >> 7), inner = rem & 127;
    xa16[c] = *(const u32x4*)(wxa + (w8g * 8 + mt) * 2048 + inner * 16);
  }
  // whole sentence slice -> LDS
  for (int i = tid; i < 2048; i += 512)
    sent_lds[i >> 9][i & 511] = sent[(b0 + (i >> 9)) * TT + (i & 511)];
  // zero h buffers (cols >=4 stay zero forever) and x buffers
  for (int i = tid; i < 512; i += 512) { }  // (nop keeper)
  for (int i = tid; i < 768; i += 512) {
    if (i < 512) acth[i >> 8][i & 255] = (u32x4){0, 0, 0, 0};
    else         xbuf[(i - 512) >> 7][(i - 512) & 127] = (u32x4){0, 0, 0, 0};
  }

  // per-lane cell geometry
  const int s = lane & 3, hul = lane >> 4, d = (lane >> 2) & 3;
  const int mt0 = 2 * d, mt1 = 2 * d + 1;
  const int hu0 = w * 32 + mt0 * 4 + hul;
  const int hu1 = w * 32 + mt1 * 4 + hul;
  const float b00 = bias[0 * 256 + hu0], b01 = bias[1 * 256 + hu0],
              b02 = bias[2 * 256 + hu0], b03 = bias[3 * 256 + hu0];
  const float b10 = bias[0 * 256 + hu1], b11 = bias[1 * 256 + hu1],
              b12 = bias[2 * 256 + hu1], b13 = bias[3 * 256 + hu1];
  const int hb0 = ((hu0 >> 7) << 11) + (((hu0 >> 5) & 3) << 9) + (((hu0 >> 4) & 1) << 8) + (s << 4) + (hu0 & 15);
  const int hb1 = ((hu1 >> 7) << 11) + (((hu1 >> 5) & 3) << 9) + (((hu1 >> 4) & 1) << 8) + (s << 4) + (hu1 & 15);
  const long ob0 = ((long)(b0 + s) * TT) * HH + hu0;
  const long ob1 = ((long)(b0 + s) * TT) * HH + hu1;
  const int gseq = lane & 3, gch = w * 2 + ((lane >> 2) & 1);  // gatherer mapping (lane<8)
  const int gw = ((gch >> 2) << 9) + (((gch >> 1) & 1) << 8) + (gseq << 4) + ((gch & 1) << 3);
  const int i0 = ((lane >> 4) << 5) + (lane & 15);

  __syncthreads();

  // prologue: gather + stash x(0), x(1)
  if (lane < 8) {
    const int ix0 = sent_lds[gseq][0];
    const u32x2 x0 = *(const u32x2*)(emb8 + (size_t)ix0 * EE + gch * 8);
    *(u32x2*)((unsigned char*)&xbuf[0][0] + gw) = x0;
    const int ix1 = sent_lds[gseq][1];
    const u32x2 x1 = *(const u32x2*)(emb8 + (size_t)ix1 * EE + gch * 8);
    *(u32x2*)((unsigned char*)&xbuf[1][0] + gw) = x1;
  }
  __syncthreads();

  const f32x4 Z = (f32x4){0.f, 0.f, 0.f, 0.f};
  f32x4 acc[8];

  // prologue x-projection for t=0 (reads xbuf[0])
  {
    const i32x8 Bx = pack8(xbuf[0][i0], xbuf[0][i0 + 16]);
#pragma unroll
    for (int mt = 0; mt < 4; ++mt) acc[mt] = mfma_mx(Ax[mt], Bx, Z);
#pragma unroll
    for (int mt = 4; mt < 8; ++mt) {
      const int tb = (w * 4 + (mt - 4)) * 128 + i0;
      acc[mt] = mfma_mx(pack8(xa16[tb], xa16[tb + 16]), Bx, Z);
    }
  }

  float cs0 = 0.f, cs1 = 0.f;

#pragma unroll 1
  for (int t = 0; t < TT; ++t) {
    const int cur = t & 1, nxt = cur ^ 1;

    // distance-2 emb gather: x(t+2), stashed at end of this step
    u32x2 xr;
    const bool dog = (lane < 8) && (t + 2 < TT);
    if (dog) {
      const int idx = sent_lds[gseq][t + 2];
      xr = *(const u32x2*)(emb8 + (size_t)idx * EE + gch * 8);
    }

    // ---- 16 h-MFMAs accumulate onto preloaded x-contrib(t) ----
    const i32x8 Bh0 = pack8(acth[cur][i0], acth[cur][i0 + 16]);
    const i32x8 Bh1 = pack8(acth[cur][128 + i0], acth[cur][128 + i0 + 16]);
#pragma unroll
    for (int mt = 0; mt < 8; ++mt) acc[mt] = mfma_mx(Ah[mt][0], Bh0, acc[mt]);
#pragma unroll
    for (int mt = 0; mt < 8; ++mt) acc[mt] = mfma_mx(Ah[mt][1], Bh1, acc[mt]);

    // ---- redist write captures gates(t) ----
    if ((lane & 15) < 4) {
#pragma unroll
      for (int mt = 0; mt < 8; ++mt)
        *(f32x4*)&redist[w][mt][hul][lane & 3][0] = acc[mt];
    }

    // ---- x-projection for t+1 re-initializes acc; drains under activation ----
    {
      const int xpar = (t + 1) & 1;
      const i32x8 Bx = pack8(xbuf[xpar][i0], xbuf[xpar][i0 + 16]);
#pragma unroll
      for (int mt = 0; mt < 4; ++mt) acc[mt] = mfma_mx(Ax[mt], Bx, Z);
#pragma unroll
      for (int mt = 4; mt < 8; ++mt) {
        const int tb = (w * 4 + (mt - 4)) * 128 + i0;
        acc[mt] = mfma_mx(pack8(xa16[tb], xa16[tb + 16]), Bx, Z);
      }
    }

    asm volatile("s_waitcnt lgkmcnt(0)" ::: "memory");
    __builtin_amdgcn_sched_barrier(0);
    const f32x4 g0 = *(const f32x4*)&redist[w][mt0][hul][s][0];
    const f32x4 g1 = *(const f32x4*)&redist[w][mt1][hul][s][0];

    // ---- 2 LSTM cells per thread (exp2-folded) ----
    float si, sf, so, tg, tc, hv0, hv1;
    si = rcp_f(1.f + exp2_(g0[0] * SN_ + b00));
    sf = rcp_f(1.f + exp2_(g0[1] * SN_ + b01));
    tg = 2.f * rcp_f(1.f + exp2_(g0[2] * SG_ + b02)) - 1.f;
    so = rcp_f(1.f + exp2_(g0[3] * SN_ + b03));
    cs0 = sf * cs0 + si * tg;
    tc = 2.f * rcp_f(1.f + exp2_(cs0 * C2_)) - 1.f;
    hv0 = so * tc;
    si = rcp_f(1.f + exp2_(g1[0] * SN_ + b10));
    sf = rcp_f(1.f + exp2_(g1[1] * SN_ + b11));
    tg = 2.f * rcp_f(1.f + exp2_(g1[2] * SG_ + b12)) - 1.f;
    so = rcp_f(1.f + exp2_(g1[3] * SN_ + b13));
    cs1 = sf * cs1 + si * tg;
    tc = 2.f * rcp_f(1.f + exp2_(cs1 * C2_)) - 1.f;
    hv1 = so * tc;

    // h(t) fp8 x16 into next h buffer; bf16 to global (un-drained)
    unsigned char* An = (unsigned char*)&acth[nxt][0];
    const int pk = __builtin_amdgcn_cvt_pk_fp8_f32(16.f * hv0, 16.f * hv1, 0, false);
    An[hb0] = (unsigned char)(pk & 0xff);
    An[hb1] = (unsigned char)((pk >> 8) & 0xff);
    lstm_out[ob0 + (long)t * HH] = to_bf16(hv0);
    lstm_out[ob1 + (long)t * HH] = to_bf16(hv1);

    // stash x(t+2) into xbuf[t&1] (opposite parity from this step's x read)
    if (dog) *(u32x2*)((unsigned char*)&xbuf[cur][0] + gw) = xr;

    // barrier WITHOUT vmcnt drain: LDS visibility only
    asm volatile("s_waitcnt lgkmcnt(0)" ::: "memory");
    __builtin_amdgcn_s_barrier();
  }
}

// ---------------- logits = lstm_out @ W_lin^T + b_lin ----------------
__global__ __launch_bounds__(256)
void logits_gemm(const unsigned short* __restrict__ lstm, const unsigned short* __restrict__ wl,
                 const float* __restrict__ blin, float* __restrict__ logits) {
  const int tid = threadIdx.x, l = tid & 63, wv = tid >> 6;
  const long m0 = (long)blockIdx.x * 64 + wv * 16;
  f32x4 ac[4];
#pragma unroll
  for (int q = 0; q < 4; ++q) ac[q] = (f32x4){0.f, 0.f, 0.f, 0.f};
  const unsigned short* arow = lstm + (m0 + (l & 15)) * HH + ((l >> 4) << 3);
#pragma unroll
  for (int kk = 0; kk < 8; ++kk) {
    const bf16x8_t a = __builtin_bit_cast(bf16x8_t, *(const u32x4*)(arow + kk * 32));
#pragma unroll
    for (int q = 0; q < 4; ++q) {
      const bf16x8_t b = __builtin_bit_cast(bf16x8_t, *(const u32x4*)(wl + (((q * 8 + kk) * 64 + l) << 3)));
      ac[q] = __builtin_amdgcn_mfma_f32_16x16x32_bf16(a, b, ac[q], 0, 0, 0);
    }
  }
  const int r0 = (l >> 4) << 2;
#pragma unroll
  for (int q = 0; q < 4; ++q) {
    const int col = q * 16 + (l & 15);
    const float bb = blin[col];
#pragma unroll
    for (int r = 0; r < 4; ++r)
      logits[(m0 + r0 + r) * CC + col] = ac[q][r] + bb;
  }
}

// ------------- log_softmax over time + product over time, per (b,c) -------------
// True product overflows fp32/fp64 (ref = +inf). Accumulate log2|logp| and emit
// exp2(min(sum,127)): exact when representable, finite otherwise (never inf/nan).
__global__ __launch_bounds__(256)
void softmax_prod(const float* __restrict__ logits, float* __restrict__ out) {
  __shared__ float lds[TT * CC];   // 128 KB
  __shared__ float red[3][4][CC];
  const int tid = threadIdx.x, b = blockIdx.x;
  const f32x4* src = (const f32x4*)(logits + (long)b * TT * CC);
  f32x4* dst = (f32x4*)lds;
#pragma unroll 1
  for (int i = tid; i < TT * CC / 4; i += 256) dst[i] = src[i];
  __syncthreads();

  const int c = tid & 63, part = tid >> 6;
  const int t0 = part * 128;
  float m = -3.0e38f;
  for (int k = 0; k < 128; ++k) m = fmaxf(m, lds[(t0 + k) * CC + c]);
  red[0][part][c] = m;
  __syncthreads();
  m = fmaxf(fmaxf(red[0][0][c], red[0][1][c]), fmaxf(red[0][2][c], red[0][3][c]));

  float ssum = 0.f;
  for (int k = 0; k < 128; ++k) ssum += __expf(lds[(t0 + k) * CC + c] - m);
  red[1][part][c] = ssum;
  __syncthreads();
  ssum = red[1][0][c] + red[1][1][c] + red[1][2][c] + red[1][3][c];
  const float lse = m + __logf(ssum);

  float pacc = 0.f;
  for (int k = 0; k < 128; ++k) pacc += __log2f(fabsf(lds[(t0 + k) * CC + c] - lse));
  red[2][part][c] = pacc;
  __syncthreads();
  if (part == 0) {
    const float tot = red[2][0][c] + red[2][1][c] + red[2][2][c] + red[2][3][c];
    out[b * CC + c] = exp2f(fminf(tot, 127.0f));
  }
}

extern "C" void kernel_launch(void* const* d_in, const int* in_sizes, int n_in,
                              void* d_out, int out_size, void* d_ws, size_t ws_size,
                              hipStream_t stream) {
  (void)in_sizes; (void)n_in; (void)out_size;
  if (ws_size < WS_NEED) return;  // produces 0-node graph -> explicit harness error

  const int*   sent = (const int*)d_in[0];
  const float* emb  = (const float*)d_in[1];
  const float* Wih  = (const float*)d_in[2];
  const float* Whh  = (const float*)d_in[3];
  const float* bih  = (const float*)d_in[4];
  const float* bhh  = (const float*)d_in[5];
  const float* Wlin = (const float*)d_in[6];
  const float* blin = (const float*)d_in[7];
  float* out = (float*)d_out;
  char* ws = (char*)d_ws;

  unsigned char*  emb8 = (unsigned char*)(ws + OFF_EMB);
  unsigned char*  wha  = (unsigned char*)(ws + OFF_WHA);
  unsigned char*  wxa  = (unsigned char*)(ws + OFF_WXA);
  float*          bp   = (float*)(ws + OFF_BIAS);
  unsigned short* wl   = (unsigned short*)(ws + OFF_WLIN);
  unsigned short* lo   = (unsigned short*)(ws + OFF_LSTM);
  float*          lg   = (float*)(ws + OFF_LOG);

  prep_emb<<<1024, 256, 0, stream>>>(emb, (unsigned*)emb8);
  prep_wha<<<1024, 256, 0, stream>>>(Whh, wha);
  prep_wxa<<<512, 256, 0, stream>>>(Wih, wxa);
  prep_bias<<<4, 256, 0, stream>>>(bih, bhh, bp);
  prep_wlin<<<64, 256, 0, stream>>>(Wlin, wl);
  lstm_scan<<<64, 512, 0, stream>>>(sent, emb8, wha, wxa, bp, lo);
  logits_gemm<<<2048, 256, 0, stream>>>(lo, wl, blin, lg);
  softmax_prod<<<256, 256, 0, stream>>>(lg, out);
}

// Round 8
// 633.848 us; speedup vs baseline: 2.1890x; 1.3042x over previous
//
#include <hip/hip_runtime.h>

#define TT 512
#define HH 256
#define EE 128
#define BB 256
#define CC 64
#define VV 50000
#define NSB 128  // TT/4 super-steps

// workspace offsets (bytes), all 256-aligned
#define OFF_EMB   0ull           // 50000*128       = 6,400,000   (emb as fp8)
#define OFF_WHA   6400000ull     // 8*8*2*2048      =   262,144   (W_hh MX A-frags, flat lane*32)
#define OFF_WXA   6662144ull     // 8*8*64*32      =   131,072   (W_ih MX A-frags, flat lane*32)
#define OFF_BIAS  6793216ull     // 1024*4          =     4,096   (pre-scaled biases)
#define OFF_WLIN  6797312ull     // 4*8*64*8*2      =    16,384   (W_lin bf16 frags)
#define OFF_LSTM  6813696ull     // 256*512*256*2   = 67,108,864  (lstm_out bf16)
#define OFF_LOG   73922560ull    // 256*512*64*4    = 33,554,432  (logits f32)
#define WS_NEED   107476992ull

typedef __attribute__((ext_vector_type(4))) float    f32x4;
typedef __attribute__((ext_vector_type(4))) unsigned u32x4;
typedef __attribute__((ext_vector_type(8))) int      i32x8;
typedef int i32x8u __attribute__((ext_vector_type(8), aligned(16)));  // 16B-aligned view
typedef __bf16 bf16x8_t __attribute__((ext_vector_type(8)));

__device__ __forceinline__ float rcp_f(float x) { return __builtin_amdgcn_rcpf(x); }
__device__ __forceinline__ float exp2_(float x) {
  float r; asm("v_exp_f32 %0, %1" : "=v"(r) : "v"(x)); return r;
}
__device__ __forceinline__ unsigned short to_bf16(float f) {
  unsigned u = __float_as_uint(f);
  return (unsigned short)((u + 0x7fffu + ((u >> 16) & 1u)) >> 16);
}
// MX-scaled fp8 GEMM, K=128, all scale exponents = 127 (x1.0) -> plain fp8 at 2x rate
__device__ __forceinline__ f32x4 mfma_mx(i32x8 a, i32x8 b, f32x4 c) {
  return __builtin_amdgcn_mfma_scale_f32_16x16x128_f8f6f4(
      a, b, c, 0, 0, 0, 0x7f7f7f7f, 0, 0x7f7f7f7f);
}

#define LOG2E  1.442695041f
#define SN_    (-LOG2E / 1024.f)
#define SG_    (-2.f * LOG2E / 1024.f)
#define C2_    (-2.f * LOG2E)

// ---------------- prep: emb fp32 -> fp8 e4m3 (unscaled) ----------------
__global__ void prep_emb(const float* __restrict__ emb, unsigned* __restrict__ out) {
  const int stride = gridDim.x * blockDim.x;
  for (int u = blockIdx.x * blockDim.x + threadIdx.x; u < (VV * EE / 4); u += stride) {
    const f32x4 f = ((const f32x4*)emb)[u];
    int r = __builtin_amdgcn_cvt_pk_fp8_f32(f[0], f[1], 0, false);
    r = __builtin_amdgcn_cvt_pk_fp8_f32(f[2], f[3], r, true);
    out[u] = (unsigned)r;
  }
}

// ------- prep: W_hh*64 -> MX A-fragments, flat (tile*2048 + lane*32 + b) -------
// lane l: A-row r = l&15 (= hul*4+gate), k = kt*128 + (l>>4)*32 + b
__global__ void prep_wha(const float* __restrict__ Whh, unsigned char* __restrict__ wf) {
  const int id = blockIdx.x * 256 + threadIdx.x;  // exactly 262144 threads
  const int b = id & 31, l = (id >> 5) & 63;
  const int kt = (id >> 11) & 1, mt = (id >> 12) & 7, w8 = id >> 15;
  const int r16 = l & 15;
  const int grow = (r16 & 3) * 256 + (w8 * 32 + mt * 4 + (r16 >> 2));
  const int k = kt * 128 + ((l >> 4) << 5) + b;
  const int r = __builtin_amdgcn_cvt_pk_fp8_f32(64.f * Whh[grow * HH + k], 0.f, 0, false);
  wf[id] = (unsigned char)(r & 0xff);
}

// ------- prep: W_ih*1024 -> MX A-fragments, flat (tile*2048 + lane*32 + b), K=128 -------
__global__ void prep_wxa(const float* __restrict__ Wih, unsigned char* __restrict__ wf) {
  const int id = blockIdx.x * 256 + threadIdx.x;  // exactly 131072 threads
  const int b = id & 31, l = (id >> 5) & 63;
  const int mt = (id >> 11) & 7, w8 = id >> 14;
  const int r16 = l & 15;
  const int grow = (r16 & 3) * 256 + (w8 * 32 + mt * 4 + (r16 >> 2));
  const int k = ((l >> 4) << 5) + b;
  const int r = __builtin_amdgcn_cvt_pk_fp8_f32(1024.f * Wih[grow * EE + k], 0.f, 0, false);
  wf[id] = (unsigned char)(r & 0xff);
}

// bias pre-scaled for exp2-based activations
__global__ void prep_bias(const float* __restrict__ bih, const float* __restrict__ bhh,
                          float* __restrict__ bp) {
  const int n = blockIdx.x * 256 + threadIdx.x;  // 1024 threads, [gate][hu]
  const float sc = (n >= 512 && n < 768) ? (-2.f * LOG2E) : (-LOG2E);
  bp[n] = (bih[n] + bhh[n]) * sc;
}

__global__ void prep_wlin(const float* __restrict__ Wlin, unsigned short* __restrict__ wl) {
  const int id = blockIdx.x * 256 + threadIdx.x;  // 16384 threads
  const int j = id & 7, l = (id >> 3) & 63;
  const int kk = (id >> 9) & 7, q = id >> 12;
  const int c = q * 16 + (l & 15);
  const int k = kk * 32 + ((l >> 4) << 3) + j;
  wl[id] = to_bf16(Wlin[c * HH + k]);
}

// ---------------- persistent LSTM scan: 64 blocks x 512 thr, 4 seqs, 4-step batched x ----------
// Padded-flat LDS frag layout per K-128 tile (2304 B): byte(k-lane chunk) at
//   lane*32 + (lane>>2)*16 + (k&31), lane = ((k>>5)<<4) + (row/col).
// acc cols = j*4 + s (micro-step j, seq s). B-h invariant: entering micro-step j only
// cols j*4+s nonzero (each thread zeroes consumed col, writes h to col (j+1)*4+s).
// x-proj for 4 steps re-inits acc once per super-step (8 MFMAs/wave).
__global__ __launch_bounds__(512, 1)
void lstm_scan(const int* __restrict__ sent, const unsigned char* __restrict__ emb8,
               const unsigned char* __restrict__ wha, const unsigned char* __restrict__ wxa,
               const float* __restrict__ bias, unsigned short* __restrict__ lstm_out) {
  __shared__ __align__(16) unsigned char xa[32 * 2304];    // 73,728 B: W_ih mt4..7 per wave
  __shared__ __align__(16) unsigned char bh[2 * 2304];     //  4,608 B: h B-frags (rotating)
  __shared__ __align__(16) unsigned char xbuf[2][2304];    //  4,608 B: x B-frags
  __shared__ __align__(16) float redist[8][8][4][4][4];    // 16,384 B
  __shared__ int sent_lds[4][512];                         //  8,192 B  -> ~105 KB

  const int tid = threadIdx.x;
  const int lane = tid & 63;
  const int w = tid >> 6;
  const int b0 = blockIdx.x << 2;

  // ---- one-time staging ----
  i32x8 Ah[8][2];
#pragma unroll
  for (int mt = 0; mt < 8; ++mt)
#pragma unroll
    for (int kt = 0; kt < 2; ++kt)
      Ah[mt][kt] = *(const i32x8*)(wha + ((w * 8 + mt) * 2 + kt) * 2048 + lane * 32);
  i32x8 Ax[4];
#pragma unroll
  for (int mtx = 0; mtx < 4; ++mtx)
    Ax[mtx] = *(const i32x8*)(wxa + ((w * 8 + mtx) * 64 + lane) * 32);

  // W_ih mt4..7 -> LDS with pad transform
  for (int c = tid; c < 4096; c += 512) {
    const int tile = c >> 7, i = c & 127, ln = i >> 1, hf = i & 1;
    const int w8 = tile >> 2, mtx = tile & 3;
    *(u32x4*)(xa + tile * 2304 + ln * 32 + (ln >> 2) * 16 + hf * 16) =
        *(const u32x4*)(wxa + ((w8 * 8 + 4 + mtx) * 64 + ln) * 32 + hf * 16);
  }
  for (int i = tid; i < 2048; i += 512)
    sent_lds[i >> 9][i & 511] = sent[(b0 + (i >> 9)) * TT + (i & 511)];
  for (int i = tid; i < 1152; i += 512) ((int*)bh)[i] = 0;
  __syncthreads();

  // prologue gather x(0..3) -> xbuf[0]: wave w rows 2w,2w+1; lane<16: chunk q=lane&7
  if (lane < 16) {
    const int r = 2 * w + (lane >> 3), q = lane & 7;
    const int idx = sent_lds[r & 3][r >> 2];
    const u32x4 v = *(const u32x4*)(emb8 + (size_t)idx * EE + q * 16);
    *(u32x4*)(xbuf[0] + (q >> 1) * 576 + (q & 1) * 16 + r * 32 + (r >> 2) * 16) = v;
  }
  __syncthreads();

  const int lread = lane * 32 + (lane >> 2) * 16;
  const f32x4 Zf = (f32x4){0.f, 0.f, 0.f, 0.f};
  f32x4 acc[8];
  {  // prologue x-proj for super-step 0
    const i32x8 Bx = __builtin_bit_cast(i32x8, *(const i32x8u*)(xbuf[0] + lread));
#pragma unroll
    for (int mtx = 0; mtx < 4; ++mtx) {
      const i32x8 Aq = __builtin_bit_cast(i32x8, *(const i32x8u*)(xa + (w * 4 + mtx) * 2304 + lread));
      acc[mtx] = mfma_mx(Ax[mtx], Bx, Zf);
      acc[4 + mtx] = mfma_mx(Aq, Bx, Zf);
    }
  }

  // per-thread geometry: source role (lane&15 = col) and target role (2 cells hu0, hu0+1)
  const int s = lane & 3;
  const int mtT = lane >> 3;
  const int hp = ((lane >> 2) & 1) << 1;
  const int hulS = lane >> 4;
  const int hu0 = w * 32 + mtT * 4 + hp;
  const float bi0 = bias[hu0],       bf0 = bias[256 + hu0],
              bg0 = bias[512 + hu0], bo0 = bias[768 + hu0];
  const float bi1 = bias[hu0 + 1],       bf1 = bias[256 + hu0 + 1],
              bg1 = bias[512 + hu0 + 1], bo1 = bias[768 + hu0 + 1];
  const int k7 = hu0 & 127;
  const int cellbase = (hu0 >> 7) * 2304 + (k7 >> 5) * 576 + (k7 & 31);
  const int s32 = s * 32;
  const long obase = ((long)(b0 + s) * TT) * HH + hu0;
  float cs0 = 0.f, cs1 = 0.f;
  u32x4 xg;

#define MICRO(J) { \
  const i32x8 Bh0 = __builtin_bit_cast(i32x8, *(const i32x8u*)(bh + lread)); \
  const i32x8 Bh1 = __builtin_bit_cast(i32x8, *(const i32x8u*)(bh + 2304 + lread)); \
  if ((J) == 0 && dog) { \
    const int r = 2 * w + (lane >> 3), q = lane & 7; \
    const int idx = sent_lds[r & 3][(tb + 1) * 4 + (r >> 2)]; \
    xg = *(const u32x4*)(emb8 + (size_t)idx * EE + q * 16); \
  } \
  _Pragma("unroll") for (int mt = 0; mt < 8; ++mt) acc[mt] = mfma_mx(Ah[mt][0], Bh0, acc[mt]); \
  _Pragma("unroll") for (int mt = 0; mt < 8; ++mt) acc[mt] = mfma_mx(Ah[mt][1], Bh1, acc[mt]); \
  if (((lane >> 2) & 3) == (J)) { \
    _Pragma("unroll") for (int mt = 0; mt < 8; ++mt) \
      *(f32x4*)&redist[w][mt][hulS][s][0] = acc[mt]; \
  } \
  if ((J) == 2 && dog) { \
    const int r = 2 * w + (lane >> 3), q = lane & 7; \
    *(u32x4*)(xbN + (q >> 1) * 576 + (q & 1) * 16 + r * 32 + (r >> 2) * 16) = xg; \
  } \
  if ((J) == 3) { \
    const i32x8 Bx = __builtin_bit_cast(i32x8, *(const i32x8u*)(xbN + lread)); \
    _Pragma("unroll") for (int mtx = 0; mtx < 4; ++mtx) { \
      const i32x8 Aq = __builtin_bit_cast(i32x8, *(const i32x8u*)(xa + (w * 4 + mtx) * 2304 + lread)); \
      acc[mtx] = mfma_mx(Ax[mtx], Bx, Zf); \
      acc[4 + mtx] = mfma_mx(Aq, Bx, Zf); \
    } \
  } \
  asm volatile("s_waitcnt lgkmcnt(0)" ::: "memory"); \
  __builtin_amdgcn_sched_barrier(0); \
  const f32x4 g0 = *(const f32x4*)&redist[w][mtT][hp][s][0]; \
  const f32x4 g1 = *(const f32x4*)&redist[w][mtT][hp + 1][s][0]; \
  float si, sf, so, tg, tc, hv0, hv1; \
  si = rcp_f(1.f + exp2_(g0[0] * SN_ + bi0)); \
  sf = rcp_f(1.f + exp2_(g0[1] * SN_ + bf0)); \
  tg = 2.f * rcp_f(1.f + exp2_(g0[2] * SG_ + bg0)) - 1.f; \
  so = rcp_f(1.f + exp2_(g0[3] * SN_ + bo0)); \
  cs0 = sf * cs0 + si * tg; \
  tc = 2.f * rcp_f(1.f + exp2_(cs0 * C2_)) - 1.f; \
  hv0 = so * tc; \
  si = rcp_f(1.f + exp2_(g1[0] * SN_ + bi1)); \
  sf = rcp_f(1.f + exp2_(g1[1] * SN_ + bf1)); \
  tg = 2.f * rcp_f(1.f + exp2_(g1[2] * SG_ + bg1)) - 1.f; \
  so = rcp_f(1.f + exp2_(g1[3] * SN_ + bo1)); \
  cs1 = sf * cs1 + si * tg; \
  tc = 2.f * rcp_f(1.f + exp2_(cs1 * C2_)) - 1.f; \
  hv1 = so * tc; \
  { \
    const int pk = __builtin_amdgcn_cvt_pk_fp8_f32(16.f * hv0, 16.f * hv1, 0, false); \
    *(unsigned short*)(bh + cellbase + s32 + ((((J) + 1) & 3)) * 144) = (unsigned short)(pk & 0xffff); \
    *(unsigned short*)(bh + cellbase + s32 + (J) * 144) = 0; \
    unsigned pb; asm("v_cvt_pk_bf16_f32 %0, %1, %2" : "=v"(pb) : "v"(hv0), "v"(hv1)); \
    *(unsigned*)(lstm_out + obase + (long)(t0 + (J)) * HH) = pb; \
  } \
  asm volatile("s_waitcnt lgkmcnt(0)" ::: "memory"); \
  __builtin_amdgcn_s_barrier(); \
}

#pragma unroll 1
  for (int tb = 0; tb < NSB; ++tb) {
    const int t0 = tb << 2;
    const bool dog = (lane < 16) && (tb + 1 < NSB);
    unsigned char* xbN = xbuf[(tb + 1) & 1];
    MICRO(0)
    MICRO(1)
    MICRO(2)
    MICRO(3)
  }
#undef MICRO
}

// ---------------- logits = lstm_out @ W_lin^T + b_lin ----------------
__global__ __launch_bounds__(256)
void logits_gemm(const unsigned short* __restrict__ lstm, const unsigned short* __restrict__ wl,
                 const float* __restrict__ blin, float* __restrict__ logits) {
  const int tid = threadIdx.x, l = tid & 63, wv = tid >> 6;
  const long m0 = (long)blockIdx.x * 64 + wv * 16;
  f32x4 ac[4];
#pragma unroll
  for (int q = 0; q < 4; ++q) ac[q] = (f32x4){0.f, 0.f, 0.f, 0.f};
  const unsigned short* arow = lstm + (m0 + (l & 15)) * HH + ((l >> 4) << 3);
#pragma unroll
  for (int kk = 0; kk < 8; ++kk) {
    const bf16x8_t a = __builtin_bit_cast(bf16x8_t, *(const u32x4*)(arow + kk * 32));
#pragma unroll
    for (int q = 0; q < 4; ++q) {
      const bf16x8_t b = __builtin_bit_cast(bf16x8_t, *(const u32x4*)(wl + (((q * 8 + kk) * 64 + l) << 3)));
      ac[q] = __builtin_amdgcn_mfma_f32_16x16x32_bf16(a, b, ac[q], 0, 0, 0);
    }
  }
  const int r0 = (l >> 4) << 2;
#pragma unroll
  for (int q = 0; q < 4; ++q) {
    const int col = q * 16 + (l & 15);
    const float bb = blin[col];
#pragma unroll
    for (int r = 0; r < 4; ++r)
      logits[(m0 + r0 + r) * CC + col] = ac[q][r] + bb;
  }
}

// ------------- log_softmax over time + product over time, per (b,c) -------------
// True product overflows fp32/fp64 (ref = +inf). Accumulate log2|logp| and emit
// exp2(min(sum,127)): exact when representable, finite otherwise (never inf/nan).
__global__ __launch_bounds__(256)
void softmax_prod(const float* __restrict__ logits, float* __restrict__ out) {
  __shared__ float lds[TT * CC];   // 128 KB
  __shared__ float red[3][4][CC];
  const int tid = threadIdx.x, b = blockIdx.x;
  const f32x4* src = (const f32x4*)(logits + (long)b * TT * CC);
  f32x4* dst = (f32x4*)lds;
#pragma unroll 1
  for (int i = tid; i < TT * CC / 4; i += 256) dst[i] = src[i];
  __syncthreads();

  const int c = tid & 63, part = tid >> 6;
  const int t0 = part * 128;
  float m = -3.0e38f;
  for (int k = 0; k < 128; ++k) m = fmaxf(m, lds[(t0 + k) * CC + c]);
  red[0][part][c] = m;
  __syncthreads();
  m = fmaxf(fmaxf(red[0][0][c], red[0][1][c]), fmaxf(red[0][2][c], red[0][3][c]));

  float ssum = 0.f;
  for (int k = 0; k < 128; ++k) ssum += __expf(lds[(t0 + k) * CC + c] - m);
  red[1][part][c] = ssum;
  __syncthreads();
  ssum = red[1][0][c] + red[1][1][c] + red[1][2][c] + red[1][3][c];
  const float lse = m + __logf(ssum);

  float pacc = 0.f;
  for (int k = 0; k < 128; ++k) pacc += __log2f(fabsf(lds[(t0 + k) * CC + c] - lse));
  red[2][part][c] = pacc;
  __syncthreads();
  if (part == 0) {
    const float tot = red[2][0][c] + red[2][1][c] + red[2][2][c] + red[2][3][c];
    out[b * CC + c] = exp2f(fminf(tot, 127.0f));
  }
}

extern "C" void kernel_launch(void* const* d_in, const int* in_sizes, int n_in,
                              void* d_out, int out_size, void* d_ws, size_t ws_size,
                              hipStream_t stream) {
  (void)in_sizes; (void)n_in; (void)out_size;
  if (ws_size < WS_NEED) return;  // produces 0-node graph -> explicit harness error

  const int*   sent = (const int*)d_in[0];
  const float* emb  = (const float*)d_in[1];
  const float* Wih  = (const float*)d_in[2];
  const float* Whh  = (const float*)d_in[3];
  const float* bih  = (const float*)d_in[4];
  const float* bhh  = (const float*)d_in[5];
  const float* Wlin = (const float*)d_in[6];
  const float* blin = (const float*)d_in[7];
  float* out = (float*)d_out;
  char* ws = (char*)d_ws;

  unsigned char*  emb8 = (unsigned char*)(ws + OFF_EMB);
  unsigned char*  wha  = (unsigned char*)(ws + OFF_WHA);
  unsigned char*  wxa  = (unsigned char*)(ws + OFF_WXA);
  float*          bp   = (float*)(ws + OFF_BIAS);
  unsigned short* wl   = (unsigned short*)(ws + OFF_WLIN);
  unsigned short* lo   = (unsigned short*)(ws + OFF_LSTM);
  float*          lg   = (float*)(ws + OFF_LOG);

  prep_emb<<<1024, 256, 0, stream>>>(emb, (unsigned*)emb8);
  prep_wha<<<1024, 256, 0, stream>>>(Whh, wha);
  prep_wxa<<<512, 256, 0, stream>>>(Wih, wxa);
  prep_bias<<<4, 256, 0, stream>>>(bih, bhh, bp);
  prep_wlin<<<64, 256, 0, stream>>>(Wlin, wl);
  lstm_scan<<<64, 512, 0, stream>>>(sent, emb8, wha, wxa, bp, lo);
  logits_gemm<<<2048, 256, 0, stream>>>(lo, wl, blin, lg);
  softmax_prod<<<256, 256, 0, stream>>>(lg, out);
}

// Round 9
// 585.322 us; speedup vs baseline: 2.3705x; 1.0829x over previous
//
#include <hip/hip_runtime.h>

#define TT 512
#define HH 256
#define EE 128
#define BB 256
#define CC 64
#define VV 50000
#define NSB 128  // TT/4 super-steps

// workspace offsets (bytes), all 256-aligned
#define OFF_EMB   0ull           // 50000*128       = 6,400,000   (emb as fp8)
#define OFF_WHA   6400000ull     // 8*8*2*2048      =   262,144   (W_hh MX A-frags, flat lane*32)
#define OFF_WXA   6662144ull     // 8*8*64*32      =   131,072   (W_ih MX A-frags, flat lane*32)
#define OFF_BIAS  6793216ull     // 1024*4          =     4,096   (pre-scaled biases)
#define OFF_WLIN  6797312ull     // 4*8*64*8*2      =    16,384   (W_lin bf16 frags)
#define OFF_LSTM  6813696ull     // 256*512*256*2   = 67,108,864  (lstm_out bf16)
#define OFF_LOG   73922560ull    // 256*512*64*4    = 33,554,432  (logits f32)
#define WS_NEED   107476992ull

typedef __attribute__((ext_vector_type(4))) float    f32x4;
typedef __attribute__((ext_vector_type(4))) unsigned u32x4;
typedef __attribute__((ext_vector_type(8))) int      i32x8;
typedef int i32x8u __attribute__((ext_vector_type(8), aligned(16)));  // 16B-aligned view
typedef __bf16 bf16x8_t __attribute__((ext_vector_type(8)));

__device__ __forceinline__ float rcp_f(float x) { return __builtin_amdgcn_rcpf(x); }
__device__ __forceinline__ float exp2_(float x) {
  float r; asm("v_exp_f32 %0, %1" : "=v"(r) : "v"(x)); return r;
}
__device__ __forceinline__ unsigned short to_bf16(float f) {
  unsigned u = __float_as_uint(f);
  return (unsigned short)((u + 0x7fffu + ((u >> 16) & 1u)) >> 16);
}
// MX-scaled fp8 GEMM, K=128, all scale exponents = 127 (x1.0) -> plain fp8 at 2x rate
__device__ __forceinline__ f32x4 mfma_mx(i32x8 a, i32x8 b, f32x4 c) {
  return __builtin_amdgcn_mfma_scale_f32_16x16x128_f8f6f4(
      a, b, c, 0, 0, 0, 0x7f7f7f7f, 0, 0x7f7f7f7f);
}

#define LOG2E  1.442695041f
#define SN_    (-LOG2E / 1024.f)
#define SG_    (-2.f * LOG2E / 1024.f)
#define C2_    (-2.f * LOG2E)

// ---------------- prep: emb fp32 -> fp8 e4m3 (unscaled) ----------------
__global__ void prep_emb(const float* __restrict__ emb, unsigned* __restrict__ out) {
  const int stride = gridDim.x * blockDim.x;
  for (int u = blockIdx.x * blockDim.x + threadIdx.x; u < (VV * EE / 4); u += stride) {
    const f32x4 f = ((const f32x4*)emb)[u];
    int r = __builtin_amdgcn_cvt_pk_fp8_f32(f[0], f[1], 0, false);
    r = __builtin_amdgcn_cvt_pk_fp8_f32(f[2], f[3], r, true);
    out[u] = (unsigned)r;
  }
}

// ------- prep: W_hh*64 -> MX A-fragments, flat (tile*2048 + lane*32 + b) -------
// lane l: A-row r = l&15 (= hul*4+gate), k = kt*128 + (l>>4)*32 + b
__global__ void prep_wha(const float* __restrict__ Whh, unsigned char* __restrict__ wf) {
  const int id = blockIdx.x * 256 + threadIdx.x;  // exactly 262144 threads
  const int b = id & 31, l = (id >> 5) & 63;
  const int kt = (id >> 11) & 1, mt = (id >> 12) & 7, w8 = id >> 15;
  const int r16 = l & 15;
  const int grow = (r16 & 3) * 256 + (w8 * 32 + mt * 4 + (r16 >> 2));
  const int k = kt * 128 + ((l >> 4) << 5) + b;
  const int r = __builtin_amdgcn_cvt_pk_fp8_f32(64.f * Whh[grow * HH + k], 0.f, 0, false);
  wf[id] = (unsigned char)(r & 0xff);
}

// ------- prep: W_ih*1024 -> MX A-fragments, flat (tile*2048 + lane*32 + b), K=128 -------
__global__ void prep_wxa(const float* __restrict__ Wih, unsigned char* __restrict__ wf) {
  const int id = blockIdx.x * 256 + threadIdx.x;  // exactly 131072 threads
  const int b = id & 31, l = (id >> 5) & 63;
  const int mt = (id >> 11) & 7, w8 = id >> 14;
  const int r16 = l & 15;
  const int grow = (r16 & 3) * 256 + (w8 * 32 + mt * 4 + (r16 >> 2));
  const int k = ((l >> 4) << 5) + b;
  const int r = __builtin_amdgcn_cvt_pk_fp8_f32(1024.f * Wih[grow * EE + k], 0.f, 0, false);
  wf[id] = (unsigned char)(r & 0xff);
}

// bias pre-scaled for exp2-based activations
__global__ void prep_bias(const float* __restrict__ bih, const float* __restrict__ bhh,
                          float* __restrict__ bp) {
  const int n = blockIdx.x * 256 + threadIdx.x;  // 1024 threads, [gate][hu]
  const float sc = (n >= 512 && n < 768) ? (-2.f * LOG2E) : (-LOG2E);
  bp[n] = (bih[n] + bhh[n]) * sc;
}

__global__ void prep_wlin(const float* __restrict__ Wlin, unsigned short* __restrict__ wl) {
  const int id = blockIdx.x * 256 + threadIdx.x;  // 16384 threads
  const int j = id & 7, l = (id >> 3) & 63;
  const int kk = (id >> 9) & 7, q = id >> 12;
  const int c = q * 16 + (l & 15);
  const int k = kk * 32 + ((l >> 4) << 3) + j;
  wl[id] = to_bf16(Wlin[c * HH + k]);
}

// ---------------- persistent LSTM scan: 64 blocks x 512 thr, 4 seqs, 4-step batched x ----------
// Padded-flat LDS frag layout per K-128 tile (2304 B): byte at lane*32 + (lane>>2)*16 + (k&31).
// acc cols = j*4 + s. B-h invariant: entering micro-step j only cols j*4+s nonzero.
// redistf: mt stride 68 dwords -> read banks ((mtT+s)*4+j)&31 = 8 dwords/bank (conflict-free);
// write (16 lanes masked) stays 2-way (free).
// emb gather at distance 4 micro-steps: load ss(tb+3) issued at tb.J2, stored (tb+1).J2.
__global__ __launch_bounds__(512, 1)
void lstm_scan(const int* __restrict__ sent, const unsigned char* __restrict__ emb8,
               const unsigned char* __restrict__ wha, const unsigned char* __restrict__ wxa,
               const float* __restrict__ bias, unsigned short* __restrict__ lstm_out) {
  __shared__ __align__(16) unsigned char xa[32 * 2304];    // 73,728 B: W_ih mt4..7 per wave
  __shared__ __align__(16) unsigned char bh[2 * 2304];     //  4,608 B: h B-frags (rotating)
  __shared__ __align__(16) unsigned char xbuf[2][2304];    //  4,608 B: x B-frags
  __shared__ __align__(16) float redistf[8][544];          // 17,408 B (mt stride 68 dwords)
  __shared__ int sent_lds[4][512];                         //  8,192 B  -> ~106 KB

  const int tid = threadIdx.x;
  const int lane = tid & 63;
  const int w = tid >> 6;
  const int b0 = blockIdx.x << 2;

  // ---- one-time staging ----
  i32x8 Ah[8][2];
#pragma unroll
  for (int mt = 0; mt < 8; ++mt)
#pragma unroll
    for (int kt = 0; kt < 2; ++kt)
      Ah[mt][kt] = *(const i32x8*)(wha + ((w * 8 + mt) * 2 + kt) * 2048 + lane * 32);
  i32x8 Ax[4];
#pragma unroll
  for (int mtx = 0; mtx < 4; ++mtx)
    Ax[mtx] = *(const i32x8*)(wxa + ((w * 8 + mtx) * 64 + lane) * 32);

  // W_ih mt4..7 -> LDS with pad transform
  for (int c = tid; c < 4096; c += 512) {
    const int tile = c >> 7, i = c & 127, ln = i >> 1, hf = i & 1;
    const int w8 = tile >> 2, mtx = tile & 3;
    *(u32x4*)(xa + tile * 2304 + ln * 32 + (ln >> 2) * 16 + hf * 16) =
        *(const u32x4*)(wxa + ((w8 * 8 + 4 + mtx) * 64 + ln) * 32 + hf * 16);
  }
  for (int i = tid; i < 2048; i += 512)
    sent_lds[i >> 9][i & 511] = sent[(b0 + (i >> 9)) * TT + (i & 511)];
  for (int i = tid; i < 1152; i += 512) ((int*)bh)[i] = 0;

  // gatherer constants (lanes < 16 of each wave)
  const int gr = 2 * w + (lane >> 3), gq = lane & 7;
  const int* sptr = &sent_lds[gr & 3][gr >> 2];
  const unsigned char* embg = emb8 + gq * 16;
  const int gwo = (gq >> 1) * 576 + (gq & 1) * 16 + gr * 32 + (gr >> 2) * 16;

  __syncthreads();

  // prologue: gather + store x super-steps 0,1; issue load for ss2
  u32x4 xg;
  if (lane < 16) {
    const int i0s = sptr[0];
    *(u32x4*)(xbuf[0] + gwo) = *(const u32x4*)(embg + (size_t)i0s * EE);
    const int i1s = sptr[4];
    *(u32x4*)(xbuf[1] + gwo) = *(const u32x4*)(embg + (size_t)i1s * EE);
    const int i2s = sptr[8];
    xg = *(const u32x4*)(embg + (size_t)i2s * EE);
  }
  __syncthreads();

  const int lread = lane * 32 + (lane >> 2) * 16;
  const f32x4 Zf = (f32x4){0.f, 0.f, 0.f, 0.f};
  f32x4 acc[8];
  {  // prologue x-proj for super-step 0
    const i32x8 Bx = __builtin_bit_cast(i32x8, *(const i32x8u*)(xbuf[0] + lread));
#pragma unroll
    for (int mtx = 0; mtx < 4; ++mtx) {
      const i32x8 Aq = __builtin_bit_cast(i32x8, *(const i32x8u*)(xa + (w * 4 + mtx) * 2304 + lread));
      acc[mtx] = mfma_mx(Ax[mtx], Bx, Zf);
      acc[4 + mtx] = mfma_mx(Aq, Bx, Zf);
    }
  }

  // per-thread geometry: source role (lane&15 = col) and target role (2 cells hu0, hu0+1)
  const int s = lane & 3;
  const int mtT = lane >> 3;
  const int hp = ((lane >> 2) & 1) << 1;
  const int hulS = lane >> 4;
  const int hu0 = w * 32 + mtT * 4 + hp;
  const float bi0 = bias[hu0],       bf0 = bias[256 + hu0],
              bg0 = bias[512 + hu0], bo0 = bias[768 + hu0];
  const float bi1 = bias[hu0 + 1],       bf1 = bias[256 + hu0 + 1],
              bg1 = bias[512 + hu0 + 1], bo1 = bias[768 + hu0 + 1];
  const int k7 = hu0 & 127;
  const int cellbase = (hu0 >> 7) * 2304 + (k7 >> 5) * 576 + (k7 & 31);
  const int s32 = s * 32;
  const int wroff = hulS * 16 + s * 4;   // redist write inner offset (dwords)
  const int rdoff = mtT * 68 + hp * 16 + s * 4;  // redist read offset (dwords)
  const long obase = ((long)(b0 + s) * TT) * HH + hu0;
  float cs0 = 0.f, cs1 = 0.f;

#define MICRO(J) { \
  const i32x8 Bh0 = __builtin_bit_cast(i32x8, *(const i32x8u*)(bh + lread)); \
  const i32x8 Bh1 = __builtin_bit_cast(i32x8, *(const i32x8u*)(bh + 2304 + lread)); \
  __builtin_amdgcn_s_setprio(1); \
  _Pragma("unroll") for (int mt = 0; mt < 8; ++mt) acc[mt] = mfma_mx(Ah[mt][0], Bh0, acc[mt]); \
  _Pragma("unroll") for (int mt = 0; mt < 8; ++mt) acc[mt] = mfma_mx(Ah[mt][1], Bh1, acc[mt]); \
  __builtin_amdgcn_s_setprio(0); \
  if (((lane >> 2) & 3) == (J)) { \
    _Pragma("unroll") for (int mt = 0; mt < 8; ++mt) \
      *(f32x4*)&redistf[w][mt * 68 + wroff] = acc[mt]; \
  } \
  if ((J) == 2) { \
    if (dogS) *(u32x4*)(xbC + gwo) = xg; \
    if (dogL) { const int idx = sptr[(tb + 3) * 4]; \
                xg = *(const u32x4*)(embg + (size_t)idx * EE); } \
  } \
  if ((J) == 3) { \
    const i32x8 Bx = __builtin_bit_cast(i32x8, *(const i32x8u*)(xbN + lread)); \
    _Pragma("unroll") for (int mtx = 0; mtx < 4; ++mtx) { \
      const i32x8 Aq = __builtin_bit_cast(i32x8, *(const i32x8u*)(xa + (w * 4 + mtx) * 2304 + lread)); \
      acc[mtx] = mfma_mx(Ax[mtx], Bx, Zf); \
      acc[4 + mtx] = mfma_mx(Aq, Bx, Zf); \
    } \
  } \
  asm volatile("s_waitcnt lgkmcnt(0)" ::: "memory"); \
  __builtin_amdgcn_sched_barrier(0); \
  const f32x4 g0 = *(const f32x4*)&redistf[w][rdoff]; \
  const f32x4 g1 = *(const f32x4*)&redistf[w][rdoff + 16]; \
  float si, sf, so, tg, tc, hv0, hv1; \
  si = rcp_f(1.f + exp2_(g0[0] * SN_ + bi0)); \
  sf = rcp_f(1.f + exp2_(g0[1] * SN_ + bf0)); \
  tg = 2.f * rcp_f(1.f + exp2_(g0[2] * SG_ + bg0)) - 1.f; \
  so = rcp_f(1.f + exp2_(g0[3] * SN_ + bo0)); \
  cs0 = sf * cs0 + si * tg; \
  tc = 2.f * rcp_f(1.f + exp2_(cs0 * C2_)) - 1.f; \
  hv0 = so * tc; \
  si = rcp_f(1.f + exp2_(g1[0] * SN_ + bi1)); \
  sf = rcp_f(1.f + exp2_(g1[1] * SN_ + bf1)); \
  tg = 2.f * rcp_f(1.f + exp2_(g1[2] * SG_ + bg1)) - 1.f; \
  so = rcp_f(1.f + exp2_(g1[3] * SN_ + bo1)); \
  cs1 = sf * cs1 + si * tg; \
  tc = 2.f * rcp_f(1.f + exp2_(cs1 * C2_)) - 1.f; \
  hv1 = so * tc; \
  { \
    const int pk = __builtin_amdgcn_cvt_pk_fp8_f32(16.f * hv0, 16.f * hv1, 0, false); \
    *(unsigned short*)(bh + cellbase + s32 + ((((J) + 1) & 3)) * 144) = (unsigned short)(pk & 0xffff); \
    *(unsigned short*)(bh + cellbase + s32 + (J) * 144) = 0; \
    unsigned pb; asm("v_cvt_pk_bf16_f32 %0, %1, %2" : "=v"(pb) : "v"(hv0), "v"(hv1)); \
    *(unsigned*)(lstm_out + obase + (long)(t0 + (J)) * HH) = pb; \
  } \
  asm volatile("s_waitcnt lgkmcnt(0)" ::: "memory"); \
  __builtin_amdgcn_s_barrier(); \
}

#pragma unroll 1
  for (int tb = 0; tb < NSB; ++tb) {
    const int t0 = tb << 2;
    const bool dogS = (lane < 16) && (tb + 2 < NSB);
    const bool dogL = (lane < 16) && (tb + 3 < NSB);
    unsigned char* xbC = xbuf[tb & 1];
    unsigned char* xbN = xbuf[(tb + 1) & 1];
    MICRO(0)
    MICRO(1)
    MICRO(2)
    MICRO(3)
  }
#undef MICRO
}

// ---------------- logits = lstm_out @ W_lin^T + b_lin ----------------
__global__ __launch_bounds__(256)
void logits_gemm(const unsigned short* __restrict__ lstm, const unsigned short* __restrict__ wl,
                 const float* __restrict__ blin, float* __restrict__ logits) {
  const int tid = threadIdx.x, l = tid & 63, wv = tid >> 6;
  const long m0 = (long)blockIdx.x * 64 + wv * 16;
  f32x4 ac[4];
#pragma unroll
  for (int q = 0; q < 4; ++q) ac[q] = (f32x4){0.f, 0.f, 0.f, 0.f};
  const unsigned short* arow = lstm + (m0 + (l & 15)) * HH + ((l >> 4) << 3);
#pragma unroll
  for (int kk = 0; kk < 8; ++kk) {
    const bf16x8_t a = __builtin_bit_cast(bf16x8_t, *(const u32x4*)(arow + kk * 32));
#pragma unroll
    for (int q = 0; q < 4; ++q) {
      const bf16x8_t b = __builtin_bit_cast(bf16x8_t, *(const u32x4*)(wl + (((q * 8 + kk) * 64 + l) << 3)));
      ac[q] = __builtin_amdgcn_mfma_f32_16x16x32_bf16(a, b, ac[q], 0, 0, 0);
    }
  }
  const int r0 = (l >> 4) << 2;
#pragma unroll
  for (int q = 0; q < 4; ++q) {
    const int col = q * 16 + (l & 15);
    const float bb = blin[col];
#pragma unroll
    for (int r = 0; r < 4; ++r)
      logits[(m0 + r0 + r) * CC + col] = ac[q][r] + bb;
  }
}

// ------------- log_softmax over time + product over time, per (b,c) -------------
// True product overflows fp32/fp64 (ref = +inf). Accumulate log2|logp| and emit
// exp2(min(sum,127)): exact when representable, finite otherwise (never inf/nan).
__global__ __launch_bounds__(256)
void softmax_prod(const float* __restrict__ logits, float* __restrict__ out) {
  __shared__ float lds[TT * CC];   // 128 KB
  __shared__ float red[3][4][CC];
  const int tid = threadIdx.x, b = blockIdx.x;
  const f32x4* src = (const f32x4*)(logits + (long)b * TT * CC);
  f32x4* dst = (f32x4*)lds;
#pragma unroll 1
  for (int i = tid; i < TT * CC / 4; i += 256) dst[i] = src[i];
  __syncthreads();

  const int c = tid & 63, part = tid >> 6;
  const int t0 = part * 128;
  float m = -3.0e38f;
  for (int k = 0; k < 128; ++k) m = fmaxf(m, lds[(t0 + k) * CC + c]);
  red[0][part][c] = m;
  __syncthreads();
  m = fmaxf(fmaxf(red[0][0][c], red[0][1][c]), fmaxf(red[0][2][c], red[0][3][c]));

  float ssum = 0.f;
  for (int k = 0; k < 128; ++k) ssum += __expf(lds[(t0 + k) * CC + c] - m);
  red[1][part][c] = ssum;
  __syncthreads();
  ssum = red[1][0][c] + red[1][1][c] + red[1][2][c] + red[1][3][c];
  const float lse = m + __logf(ssum);

  float pacc = 0.f;
  for (int k = 0; k < 128; ++k) pacc += __log2f(fabsf(lds[(t0 + k) * CC + c] - lse));
  red[2][part][c] = pacc;
  __syncthreads();
  if (part == 0) {
    const float tot = red[2][0][c] + red[2][1][c] + red[2][2][c] + red[2][3][c];
    out[b * CC + c] = exp2f(fminf(tot, 127.0f));
  }
}

extern "C" void kernel_launch(void* const* d_in, const int* in_sizes, int n_in,
                              void* d_out, int out_size, void* d_ws, size_t ws_size,
                              hipStream_t stream) {
  (void)in_sizes; (void)n_in; (void)out_size;
  if (ws_size < WS_NEED) return;  // produces 0-node graph -> explicit harness error

  const int*   sent = (const int*)d_in[0];
  const float* emb  = (const float*)d_in[1];
  const float* Wih  = (const float*)d_in[2];
  const float* Whh  = (const float*)d_in[3];
  const float* bih  = (const float*)d_in[4];
  const float* bhh  = (const float*)d_in[5];
  const float* Wlin = (const float*)d_in[6];
  const float* blin = (const float*)d_in[7];
  float* out = (float*)d_out;
  char* ws = (char*)d_ws;

  unsigned char*  emb8 = (unsigned char*)(ws + OFF_EMB);
  unsigned char*  wha  = (unsigned char*)(ws + OFF_WHA);
  unsigned char*  wxa  = (unsigned char*)(ws + OFF_WXA);
  float*          bp   = (float*)(ws + OFF_BIAS);
  unsigned short* wl   = (unsigned short*)(ws + OFF_WLIN);
  unsigned short* lo   = (unsigned short*)(ws + OFF_LSTM);
  float*          lg   = (float*)(ws + OFF_LOG);

  prep_emb<<<1024, 256, 0, stream>>>(emb, (unsigned*)emb8);
  prep_wha<<<1024, 256, 0, stream>>>(Whh, wha);
  prep_wxa<<<512, 256, 0, stream>>>(Wih, wxa);
  prep_bias<<<4, 256, 0, stream>>>(bih, bhh, bp);
  prep_wlin<<<64, 256, 0, stream>>>(Wlin, wl);
  lstm_scan<<<64, 512, 0, stream>>>(sent, emb8, wha, wxa, bp, lo);
  logits_gemm<<<2048, 256, 0, stream>>>(lo, wl, blin, lg);
  softmax_prod<<<256, 256, 0, stream>>>(lg, out);
}

// Round 10
// 564.441 us; speedup vs baseline: 2.4582x; 1.0370x over previous
//
#include <hip/hip_runtime.h>

#define TT 512
#define HH 256
#define EE 128
#define BB 256
#define CC 64
#define VV 50000
#define NSB 128  // TT/4 super-steps

// workspace offsets (bytes), all 256-aligned
#define OFF_EMB   0ull           // 50000*64        = 3,200,000   (emb as fp4, x2 scale)
#define OFF_WHA   6400000ull     // 8*8*2*1024      =   131,072   (W_hh fp4 A-frags)
#define OFF_WXA   6662144ull     // 8*8*1024        =    65,536   (W_ih fp4 A-frags)
#define OFF_BIAS  6793216ull     // 1024*4          =     4,096   (pre-scaled biases)
#define OFF_WLIN  6797312ull     // 4*8*64*8*2      =    16,384   (W_lin bf16 frags)
#define OFF_LSTM  6813696ull     // 256*512*256*2   = 67,108,864  (lstm_out bf16)
#define OFF_LOG   73922560ull    // 256*512*64*4    = 33,554,432  (logits f32)
#define WS_NEED   107476992ull

typedef __attribute__((ext_vector_type(4))) float    f32x4;
typedef __attribute__((ext_vector_type(4))) unsigned u32x4;
typedef __attribute__((ext_vector_type(4))) int      i32x4;
typedef __attribute__((ext_vector_type(8))) int      i32x8;
typedef __bf16 bf16x8_t __attribute__((ext_vector_type(8)));

__device__ __forceinline__ float rcp_f(float x) { return __builtin_amdgcn_rcpf(x); }
__device__ __forceinline__ float exp2_(float x) {
  float r; asm("v_exp_f32 %0, %1" : "=v"(r) : "v"(x)); return r;
}
__device__ __forceinline__ unsigned short to_bf16(float f) {
  unsigned u = __float_as_uint(f);
  return (unsigned short)((u + 0x7fffu + ((u >> 16) & 1u)) >> 16);
}
// fp4 e2m1 round-to-nearest encoder. Grid {0,.5,1,1.5,2,3,4,6}; code = grid index.
__device__ __forceinline__ unsigned enc4(float v) {
  const unsigned sg = (__float_as_uint(v) >> 31) << 3;
  const float a = fminf(fabsf(v), 6.0f);
  const float c = (a < 2.0f) ? __builtin_rintf(a + a)
                : (a < 4.0f) ? __builtin_rintf(a) + 2.0f
                             : __builtin_rintf(a * 0.5f) + 4.0f;
  return sg | (unsigned)(int)c;
}
__device__ __forceinline__ i32x8 up8(i32x4 v) {
  i32x8 r;
  r[0] = v[0]; r[1] = v[1]; r[2] = v[2]; r[3] = v[3];
  r[4] = 0; r[5] = 0; r[6] = 0; r[7] = 0;
  return r;
}
// MX-scaled fp4 x fp4 GEMM, K=128; cbsz=blgp=4 (e2m1). sb = B-side e8m0 scales.
__device__ __forceinline__ f32x4 mfma4(i32x8 a, i32x8 b, f32x4 c, int sb) {
  return __builtin_amdgcn_mfma_scale_f32_16x16x128_f8f6f4(
      a, b, c, 4, 4, 0, 0x7f7f7f7f, 0, sb);
}
#define SB_H 0x7f7f7f7f  // x1
#define SB_X 0x80808080  // x2 (emb stored at x2 -> x-path total 64*2*2 = 256 = h-path 64*4)

#define LOG2E  1.442695041f
#define SN2    (-LOG2E / 256.f)
#define SG2    (-2.f * LOG2E / 256.f)
#define C2_    (-2.f * LOG2E)

// ---------------- prep: emb fp32 -> fp4 e2m1 (x2 scale), 8 elems/thread ----------------
__global__ void prep_emb(const float* __restrict__ emb, unsigned* __restrict__ out) {
  const int u = blockIdx.x * 256 + threadIdx.x;  // exactly 800000 threads
  const f32x4 f0 = ((const f32x4*)emb)[u * 2];
  const f32x4 f1 = ((const f32x4*)emb)[u * 2 + 1];
  unsigned r = enc4(2.f * f0[0]) | (enc4(2.f * f0[1]) << 4);
  r |= (enc4(2.f * f0[2]) | (enc4(2.f * f0[3]) << 4)) << 8;
  r |= (enc4(2.f * f1[0]) | (enc4(2.f * f1[1]) << 4)) << 16;
  r |= (enc4(2.f * f1[2]) | (enc4(2.f * f1[3]) << 4)) << 24;
  out[u] = r;
}

// ------- prep: W_hh*64 -> fp4 A-frags, flat (((w8*8+mt)*2+kt)*64 + l)*16 + byte -------
__global__ void prep_wha(const float* __restrict__ Whh, unsigned char* __restrict__ wf) {
  const int id = blockIdx.x * 256 + threadIdx.x;  // exactly 131072 threads
  const int byt = id & 15, l = (id >> 4) & 63;
  const int kt = (id >> 10) & 1, mt = (id >> 11) & 7, w8 = id >> 14;
  const int r16 = l & 15;
  const int grow = (r16 & 3) * 256 + w8 * 32 + mt * 4 + (r16 >> 2);
  const int k0 = kt * 128 + ((l >> 4) << 5) + byt * 2;
  const unsigned n0 = enc4(64.f * Whh[grow * HH + k0]);
  const unsigned n1 = enc4(64.f * Whh[grow * HH + k0 + 1]);
  wf[id] = (unsigned char)(n0 | (n1 << 4));
}

// ------- prep: W_ih*64 -> fp4 A-frags, flat ((w8*8+mt)*64 + l)*16 + byte, K=128 -------
__global__ void prep_wxa(const float* __restrict__ Wih, unsigned char* __restrict__ wf) {
  const int id = blockIdx.x * 256 + threadIdx.x;  // exactly 65536 threads
  const int byt = id & 15, l = (id >> 4) & 63;
  const int mt = (id >> 10) & 7, w8 = id >> 13;
  const int r16 = l & 15;
  const int grow = (r16 & 3) * 256 + w8 * 32 + mt * 4 + (r16 >> 2);
  const int k0 = ((l >> 4) << 5) + byt * 2;
  const unsigned n0 = enc4(64.f * Wih[grow * EE + k0]);
  const unsigned n1 = enc4(64.f * Wih[grow * EE + k0 + 1]);
  wf[id] = (unsigned char)(n0 | (n1 << 4));
}

// bias pre-scaled for exp2-based activations
__global__ void prep_bias(const float* __restrict__ bih, const float* __restrict__ bhh,
                          float* __restrict__ bp) {
  const int n = blockIdx.x * 256 + threadIdx.x;  // 1024 threads, [gate][hu]
  const float sc = (n >= 512 && n < 768) ? (-2.f * LOG2E) : (-LOG2E);
  bp[n] = (bih[n] + bhh[n]) * sc;
}

__global__ void prep_wlin(const float* __restrict__ Wlin, unsigned short* __restrict__ wl) {
  const int id = blockIdx.x * 256 + threadIdx.x;  // 16384 threads
  const int j = id & 7, l = (id >> 3) & 63;
  const int kk = (id >> 9) & 7, q = id >> 12;
  const int c = q * 16 + (l & 15);
  const int k = kk * 32 + ((l >> 4) << 3) + j;
  wl[id] = to_bf16(Wlin[c * HH + k]);
}

// ---------------- persistent LSTM scan: 64 blocks x 512 thr, 4 seqs, all-fp4 MFMA ----------
// fp4 B-tiles: 1024 B each; lane reads its 16 B at lane*16 (bank-uniform, no padding).
//   byte(col,k) within tile: ((k&127)>>5)*256 + col*16 + ((k&31)>>1), nibble k&1.
// acc cols = j*4+s. bh invariant: entering micro-step J only cols J*4+s nonzero.
// h-write: one byte = both cells (hu0, hu0+1 nibbles). W_hh frags in regs (16 tuples),
// W_ih frags in LDS (64 KB). x-proj batched per 4 steps with B-scale x2.
__global__ __launch_bounds__(512, 1)
void lstm_scan(const int* __restrict__ sent, const unsigned char* __restrict__ emb4,
               const unsigned char* __restrict__ wha, const unsigned char* __restrict__ wxa,
               const float* __restrict__ bias, unsigned short* __restrict__ lstm_out) {
  __shared__ __align__(16) unsigned char xa[64 * 1024];   // 64 KB: W_ih fp4 A-frags
  __shared__ __align__(16) unsigned char bh[2 * 1024];    //  2 KB: h B-frags (rotating cols)
  __shared__ __align__(16) unsigned char xbuf[2][1024];   //  2 KB: x B-frags (parity)
  __shared__ __align__(16) float redistf[8][544];         // 17,408 B (mt stride 68 dwords)
  __shared__ int sent_lds[4][512];                        //  8 KB   -> ~94 KB, 1 block/CU

  const int tid = threadIdx.x;
  const int lane = tid & 63;
  const int w = tid >> 6;
  const int b0 = blockIdx.x << 2;

  // ---- one-time staging ----
  i32x8 Ah[8][2];  // W_hh fp4 A-frags (low 4 regs live)
#pragma unroll
  for (int mt = 0; mt < 8; ++mt)
#pragma unroll
    for (int kt = 0; kt < 2; ++kt)
      Ah[mt][kt] = up8(*(const i32x4*)(wha + (((w * 8 + mt) * 2 + kt) * 64 + lane) * 16));

  // W_ih frags -> LDS (straight copy, flat layout matches consumption)
  for (int c = tid; c < 4096; c += 512)
    ((u32x4*)xa)[c] = ((const u32x4*)wxa)[c];
  for (int i = tid; i < 2048; i += 512)
    sent_lds[i >> 9][i & 511] = sent[(b0 + (i >> 9)) * TT + (i & 511)];
  if (tid < 512) ((int*)bh)[tid] = 0;  // h(0)=0 and all cols zero

  // gatherer constants (lanes < 8 of each wave): row gr = 2w+(lane>>2), chunk gq = lane&3
  const int gr = 2 * w + ((lane >> 2) & 1), gq = lane & 3;
  const int* sptr = &sent_lds[gr & 3][gr >> 2];
  const unsigned char* embg = emb4 + gq * 16;
  const int gwo = gq * 256 + gr * 16;

  __syncthreads();

  // prologue: gather + store x super-steps 0,1; issue load for ss2
  u32x4 xg;
  if (lane < 8) {
    const int i0s = sptr[0];
    *(u32x4*)(xbuf[0] + gwo) = *(const u32x4*)(embg + (size_t)i0s * 64);
    const int i1s = sptr[4];
    *(u32x4*)(xbuf[1] + gwo) = *(const u32x4*)(embg + (size_t)i1s * 64);
    const int i2s = sptr[8];
    xg = *(const u32x4*)(embg + (size_t)i2s * 64);
  }
  __syncthreads();

  const int l16 = lane * 16;
  const f32x4 Zf = (f32x4){0.f, 0.f, 0.f, 0.f};
  f32x4 acc[8];
  {  // prologue x-proj for super-step 0 (B-scale x2)
    const i32x8 Bx = up8(*(const i32x4*)(xbuf[0] + l16));
#pragma unroll
    for (int mtx = 0; mtx < 8; ++mtx) {
      const i32x8 Aq = up8(*(const i32x4*)(xa + (w * 8 + mtx) * 1024 + l16));
      acc[mtx] = mfma4(Aq, Bx, Zf, SB_X);
    }
  }

  // per-thread geometry: source role (col = lane&15) and target role (cells hu0, hu0+1)
  const int s = lane & 3;
  const int mtT = lane >> 3;
  const int hp = ((lane >> 2) & 1) << 1;
  const int hulS = lane >> 4;
  const int hu0 = w * 32 + mtT * 4 + hp;
  const float bi0 = bias[hu0],       bf0 = bias[256 + hu0],
              bg0 = bias[512 + hu0], bo0 = bias[768 + hu0];
  const float bi1 = bias[hu0 + 1],       bf1 = bias[256 + hu0 + 1],
              bg1 = bias[512 + hu0 + 1], bo1 = bias[768 + hu0 + 1];
  // bh byte base for this thread's cell pair (col term s*16 folded in; j term added per step)
  const int cb4 = (hu0 >> 7) * 1024 + ((hu0 & 127) >> 5) * 256 + s * 16 + ((hu0 & 31) >> 1);
  const int wroff = hulS * 16 + s * 4;            // redist write inner offset (dwords)
  const int rdoff = mtT * 68 + hp * 16 + s * 4;   // redist read offset (dwords)
  const long obase = ((long)(b0 + s) * TT) * HH + hu0;
  float cs0 = 0.f, cs1 = 0.f;

#define MICRO(J) { \
  const i32x8 Bh0 = up8(*(const i32x4*)(bh + l16)); \
  const i32x8 Bh1 = up8(*(const i32x4*)(bh + 1024 + l16)); \
  __builtin_amdgcn_s_setprio(1); \
  _Pragma("unroll") for (int mt = 0; mt < 8; ++mt) acc[mt] = mfma4(Ah[mt][0], Bh0, acc[mt], SB_H); \
  _Pragma("unroll") for (int mt = 0; mt < 8; ++mt) acc[mt] = mfma4(Ah[mt][1], Bh1, acc[mt], SB_H); \
  __builtin_amdgcn_s_setprio(0); \
  if (((lane >> 2) & 3) == (J)) { \
    _Pragma("unroll") for (int mt = 0; mt < 8; ++mt) \
      *(f32x4*)&redistf[w][mt * 68 + wroff] = acc[mt]; \
  } \
  if ((J) == 2) { \
    if (dogS) *(u32x4*)(xbC + gwo) = xg; \
    if (dogL) { const int idx = sptr[(tb + 3) * 4]; \
                xg = *(const u32x4*)(embg + (size_t)idx * 64); } \
  } \
  if ((J) == 3) { \
    const i32x8 Bx = up8(*(const i32x4*)(xbN + l16)); \
    _Pragma("unroll") for (int mtx = 0; mtx < 8; ++mtx) { \
      const i32x8 Aq = up8(*(const i32x4*)(xa + (w * 8 + mtx) * 1024 + l16)); \
      acc[mtx] = mfma4(Aq, Bx, Zf, SB_X); \
    } \
  } \
  asm volatile("s_waitcnt lgkmcnt(0)" ::: "memory"); \
  __builtin_amdgcn_sched_barrier(0); \
  const f32x4 g0 = *(const f32x4*)&redistf[w][rdoff]; \
  const f32x4 g1 = *(const f32x4*)&redistf[w][rdoff + 16]; \
  float si, sf, so, tg, tc, hv0, hv1; \
  si = rcp_f(1.f + exp2_(g0[0] * SN2 + bi0)); \
  sf = rcp_f(1.f + exp2_(g0[1] * SN2 + bf0)); \
  tg = 2.f * rcp_f(1.f + exp2_(g0[2] * SG2 + bg0)) - 1.f; \
  so = rcp_f(1.f + exp2_(g0[3] * SN2 + bo0)); \
  cs0 = sf * cs0 + si * tg; \
  tc = 2.f * rcp_f(1.f + exp2_(cs0 * C2_)) - 1.f; \
  hv0 = so * tc; \
  si = rcp_f(1.f + exp2_(g1[0] * SN2 + bi1)); \
  sf = rcp_f(1.f + exp2_(g1[1] * SN2 + bf1)); \
  tg = 2.f * rcp_f(1.f + exp2_(g1[2] * SG2 + bg1)) - 1.f; \
  so = rcp_f(1.f + exp2_(g1[3] * SN2 + bo1)); \
  cs1 = sf * cs1 + si * tg; \
  tc = 2.f * rcp_f(1.f + exp2_(cs1 * C2_)) - 1.f; \
  hv1 = so * tc; \
  { \
    const unsigned nib = enc4(4.f * hv0) | (enc4(4.f * hv1) << 4); \
    bh[cb4 + ((((J) + 1) & 3)) * 64] = (unsigned char)nib; \
    bh[cb4 + (J) * 64] = 0; \
    unsigned pb; asm("v_cvt_pk_bf16_f32 %0, %1, %2" : "=v"(pb) : "v"(hv0), "v"(hv1)); \
    *(unsigned*)(lstm_out + obase + (long)(t0 + (J)) * HH) = pb; \
  } \
  asm volatile("s_waitcnt lgkmcnt(0)" ::: "memory"); \
  __builtin_amdgcn_s_barrier(); \
}

#pragma unroll 1
  for (int tb = 0; tb < NSB; ++tb) {
    const int t0 = tb << 2;
    const bool dogS = (lane < 8) && (tb + 2 < NSB);
    const bool dogL = (lane < 8) && (tb + 3 < NSB);
    unsigned char* xbC = xbuf[tb & 1];
    unsigned char* xbN = xbuf[(tb + 1) & 1];
    MICRO(0)
    MICRO(1)
    MICRO(2)
    MICRO(3)
  }
#undef MICRO
}

// ---------------- logits = lstm_out @ W_lin^T + b_lin ----------------
__global__ __launch_bounds__(256)
void logits_gemm(const unsigned short* __restrict__ lstm, const unsigned short* __restrict__ wl,
                 const float* __restrict__ blin, float* __restrict__ logits) {
  const int tid = threadIdx.x, l = tid & 63, wv = tid >> 6;
  const long m0 = (long)blockIdx.x * 64 + wv * 16;
  f32x4 ac[4];
#pragma unroll
  for (int q = 0; q < 4; ++q) ac[q] = (f32x4){0.f, 0.f, 0.f, 0.f};
  const unsigned short* arow = lstm + (m0 + (l & 15)) * HH + ((l >> 4) << 3);
#pragma unroll
  for (int kk = 0; kk < 8; ++kk) {
    const bf16x8_t a = __builtin_bit_cast(bf16x8_t, *(const u32x4*)(arow + kk * 32));
#pragma unroll
    for (int q = 0; q < 4; ++q) {
      const bf16x8_t b = __builtin_bit_cast(bf16x8_t, *(const u32x4*)(wl + (((q * 8 + kk) * 64 + l) << 3)));
      ac[q] = __builtin_amdgcn_mfma_f32_16x16x32_bf16(a, b, ac[q], 0, 0, 0);
    }
  }
  const int r0 = (l >> 4) << 2;
#pragma unroll
  for (int q = 0; q < 4; ++q) {
    const int col = q * 16 + (l & 15);
    const float bb = blin[col];
#pragma unroll
    for (int r = 0; r < 4; ++r)
      logits[(m0 + r0 + r) * CC + col] = ac[q][r] + bb;
  }
}

// ------------- log_softmax over time + product over time, per (b,c) -------------
// True product overflows fp32/fp64 (ref = +inf). Accumulate log2|logp| and emit
// exp2(min(sum,127)): exact when representable, finite otherwise (never inf/nan).
__global__ __launch_bounds__(256)
void softmax_prod(const float* __restrict__ logits, float* __restrict__ out) {
  __shared__ float lds[TT * CC];   // 128 KB
  __shared__ float red[3][4][CC];
  const int tid = threadIdx.x, b = blockIdx.x;
  const f32x4* src = (const f32x4*)(logits + (long)b * TT * CC);
  f32x4* dst = (f32x4*)lds;
#pragma unroll 1
  for (int i = tid; i < TT * CC / 4; i += 256) dst[i] = src[i];
  __syncthreads();

  const int c = tid & 63, part = tid >> 6;
  const int t0 = part * 128;
  float m = -3.0e38f;
  for (int k = 0; k < 128; ++k) m = fmaxf(m, lds[(t0 + k) * CC + c]);
  red[0][part][c] = m;
  __syncthreads();
  m = fmaxf(fmaxf(red[0][0][c], red[0][1][c]), fmaxf(red[0][2][c], red[0][3][c]));

  float ssum = 0.f;
  for (int k = 0; k < 128; ++k) ssum += __expf(lds[(t0 + k) * CC + c] - m);
  red[1][part][c] = ssum;
  __syncthreads();
  ssum = red[1][0][c] + red[1][1][c] + red[1][2][c] + red[1][3][c];
  const float lse = m + __logf(ssum);

  float pacc = 0.f;
  for (int k = 0; k < 128; ++k) pacc += __log2f(fabsf(lds[(t0 + k) * CC + c] - lse));
  red[2][part][c] = pacc;
  __syncthreads();
  if (part == 0) {
    const float tot = red[2][0][c] + red[2][1][c] + red[2][2][c] + red[2][3][c];
    out[b * CC + c] = exp2f(fminf(tot, 127.0f));
  }
}

extern "C" void kernel_launch(void* const* d_in, const int* in_sizes, int n_in,
                              void* d_out, int out_size, void* d_ws, size_t ws_size,
                              hipStream_t stream) {
  (void)in_sizes; (void)n_in; (void)out_size;
  if (ws_size < WS_NEED) return;  // produces 0-node graph -> explicit harness error

  const int*   sent = (const int*)d_in[0];
  const float* emb  = (const float*)d_in[1];
  const float* Wih  = (const float*)d_in[2];
  const float* Whh  = (const float*)d_in[3];
  const float* bih  = (const float*)d_in[4];
  const float* bhh  = (const float*)d_in[5];
  const float* Wlin = (const float*)d_in[6];
  const float* blin = (const float*)d_in[7];
  float* out = (float*)d_out;
  char* ws = (char*)d_ws;

  unsigned char*  emb4 = (unsigned char*)(ws + OFF_EMB);
  unsigned char*  wha  = (unsigned char*)(ws + OFF_WHA);
  unsigned char*  wxa  = (unsigned char*)(ws + OFF_WXA);
  float*          bp   = (float*)(ws + OFF_BIAS);
  unsigned short* wl   = (unsigned short*)(ws + OFF_WLIN);
  unsigned short* lo   = (unsigned short*)(ws + OFF_LSTM);
  float*          lg   = (float*)(ws + OFF_LOG);

  prep_emb<<<3125, 256, 0, stream>>>(emb, (unsigned*)emb4);
  prep_wha<<<512, 256, 0, stream>>>(Whh, wha);
  prep_wxa<<<256, 256, 0, stream>>>(Wih, wxa);
  prep_bias<<<4, 256, 0, stream>>>(bih, bhh, bp);
  prep_wlin<<<64, 256, 0, stream>>>(Wlin, wl);
  lstm_scan<<<64, 512, 0, stream>>>(sent, emb4, wha, wxa, bp, lo);
  logits_gemm<<<2048, 256, 0, stream>>>(lo, wl, blin, lg);
  softmax_prod<<<256, 256, 0, stream>>>(lg, out);
}